// Round 15
// baseline (652.847 us; speedup 1.0000x reference)
//
#include <hip/hip_runtime.h>
#include <hip/hip_bf16.h>
#include <math.h>

#define D_ 1024
#define DI_ 2048
#define HS_ 16
#define PS_ 128
#define NS_ 64
#define HA_ 16
#define HKV_ 4
#define PA_ 64
#define B_ 2
#define L_ 2048
#define NT_ 4096          // B_*L_
#define NC_ 32            // L_/64
#define RMS_EPS_ 1.1920929e-7f

typedef __attribute__((ext_vector_type(8))) short short8;
typedef __attribute__((ext_vector_type(4))) short short4v;
typedef __attribute__((ext_vector_type(4))) float f32x4;

#define GLOAD_LDS16(gp, lp)                                                        \
  __builtin_amdgcn_global_load_lds(                                               \
      (const __attribute__((address_space(1))) unsigned int*)(gp),                \
      (__attribute__((address_space(3))) unsigned int*)(lp), 16, 0, 0)

__device__ __forceinline__ float b2f(unsigned short u) {
  union { unsigned int i; float f; } x;
  x.i = ((unsigned int)u) << 16;
  return x.f;
}

// ---------------- transpose + fp32->bf16: W[K rows x N cols, row-stride ldw] -> Wt[N][K] ----------------
__global__ __launch_bounds__(256) void transpose_cvt(
    const float* __restrict__ W, __hip_bfloat16* __restrict__ Wt, int K, int N, int ldw) {
  __shared__ float t[32][33];
  int n0 = blockIdx.x * 32, k0 = blockIdx.y * 32;
  int tx = threadIdx.x & 31, ty = threadIdx.x >> 5;
#pragma unroll
  for (int i = 0; i < 4; i++)
    t[ty + i * 8][tx] = W[(size_t)(k0 + ty + i * 8) * ldw + n0 + tx];
  __syncthreads();
#pragma unroll
  for (int i = 0; i < 4; i++)
    Wt[(size_t)(n0 + ty + i * 8) * K + k0 + tx] = __float2bfloat16(t[tx][ty + i * 8]);
}

// ---------------- transpose bf16 -> bf16 ----------------
__global__ __launch_bounds__(256) void transpose_bf16(
    const unsigned short* __restrict__ S, unsigned short* __restrict__ D,
    int K, int N, int lds) {
  __shared__ unsigned short t[32][33];
  int n0 = blockIdx.x * 32, k0 = blockIdx.y * 32;
  int tx = threadIdx.x & 31, ty = threadIdx.x >> 5;
#pragma unroll
  for (int i = 0; i < 4; i++)
    t[ty + i * 8][tx] = S[(size_t)(k0 + ty + i * 8) * lds + n0 + tx];
  __syncthreads();
#pragma unroll
  for (int i = 0; i < 4; i++)
    D[(size_t)(n0 + ty + i * 8) * K + k0 + tx] = t[tx][ty + i * 8];
}

// ---------------- 256x256 tile, BK=32, 3-stage pipelined bf16 GEMM (N=4096,K=1024) ----------------
template<int MODE>
__global__ __launch_bounds__(512) void gemm256_k32(
    const unsigned short* __restrict__ A, const unsigned short* __restrict__ Wt,
    __hip_bfloat16* __restrict__ Cb, int N, int K) {
  __shared__ unsigned short As[3][256 * 32];
  __shared__ unsigned short Bs[3][256 * 32];
  int lid = blockIdx.x;
  int x = lid & 7, r = lid >> 3;
  int bm = ((x >> 2) * 8 + (r & 7)) * 256;
  int bn = ((x & 3) * 4 + (r >> 3)) * 256;
  int tid = threadIdx.x;
  int w = tid >> 6, l = tid & 63;
  int wr = w >> 2, wc = w & 3;
  int l15 = l & 15, lg = l >> 4;
  int rr = tid >> 2, ss = tid & 3;

  f32x4 acc[8][4];
#pragma unroll
  for (int i = 0; i < 8; i++)
#pragma unroll
    for (int j = 0; j < 4; j++) acc[i][j] = (f32x4){0.f, 0.f, 0.f, 0.f};

  auto STAGE = [&](int kt, int nb) {
    int k0 = kt * 32;
#pragma unroll
    for (int p = 0; p < 2; p++) {
      int row = p * 128 + rr;
      int kq = ss ^ ((row >> 1) & 3);
      GLOAD_LDS16(A + (size_t)(bm + row) * K + k0 + kq * 8, &As[nb][row * 32 + ss * 8]);
    }
#pragma unroll
    for (int p = 0; p < 2; p++) {
      int row = p * 128 + rr;
      int kq = ss ^ ((row >> 1) & 3);
      GLOAD_LDS16(Wt + (size_t)(bn + row) * K + k0 + kq * 8, &Bs[nb][row * 32 + ss * 8]);
    }
  };

  int KT = K >> 5;
  STAGE(0, 0);
  STAGE(1, 1);
  int buf = 0;
  for (int t = 0; t < KT; ++t) {
    if (t + 1 < KT) {
      asm volatile("s_waitcnt vmcnt(4)" ::: "memory");
    } else {
      asm volatile("s_waitcnt vmcnt(0)" ::: "memory");
    }
    __builtin_amdgcn_s_barrier();
    __builtin_amdgcn_sched_barrier(0);
    if (t + 2 < KT) STAGE(t + 2, (t + 2) % 3);
    short8 bf[4];
#pragma unroll
    for (int j = 0; j < 4; j++) {
      int row = wc * 64 + j * 16 + l15;
      bf[j] = *(const short8*)&Bs[buf][row * 32 + ((lg ^ ((row >> 1) & 3)) << 3)];
    }
#pragma unroll
    for (int i = 0; i < 8; i++) {
      int row = wr * 128 + i * 16 + l15;
      short8 af = *(const short8*)&As[buf][row * 32 + ((lg ^ ((row >> 1) & 3)) << 3)];
#pragma unroll
      for (int j = 0; j < 4; j++)
        acc[i][j] = __builtin_amdgcn_mfma_f32_16x16x32_bf16(af, bf[j], acc[i][j], 0, 0, 0);
    }
    buf = (buf == 2) ? 0 : buf + 1;
  }
#pragma unroll
  for (int i = 0; i < 8; i++)
#pragma unroll
    for (int j = 0; j < 4; j++) {
      int gr = bm + wr * 128 + i * 16 + lg * 4;
      int gc = bn + wc * 64 + j * 16 + l15;
#pragma unroll
      for (int reg = 0; reg < 4; reg++) {
        float v = acc[i][j][reg];
        if (MODE == 1) { v = fmaxf(v, 0.f); v = v * v; }
        Cb[(size_t)(gr + reg) * N + gc] = __float2bfloat16(v);
      }
    }
}

// ---------------- bf16 MFMA GEMM, BK=64 double-buffered, tile 128 x BN (BC proj) ----------------
template<int BN>
__global__ __launch_bounds__(256) void gemm_bf16_t(
    const unsigned short* __restrict__ A, const unsigned short* __restrict__ Wt,
    float* __restrict__ Cf, __hip_bfloat16* __restrict__ Cb,
    const float* __restrict__ baseb, const float* __restrict__ scale,
    int N, int K, int gn, int mode, int rsh) {
  constexpr int nWc = BN / 64;
  constexpr int nWr = 4 / nWc;
  constexpr int MF  = 8 / nWr;
  __shared__ unsigned short As[2][128 * 64];
  __shared__ unsigned short Bs[2][BN * 64];
  int lid = blockIdx.x;
  int x = lid & 7, r = lid >> 3;
  int bm, bn;
  if (rsh == 0) {
    int RN = gn >> 2;
    bm = ((x >> 2) * 16 + (r & 15)) * 128;
    bn = ((x & 3) * RN + (r >> 4)) * BN;
  } else {
    bm = (x * 4 + (r & 3)) * 128;
    bn = (r >> 2) * BN;
  }
  int tid = threadIdx.x;
  int w = tid >> 6, l = tid & 63;
  int wr = w / nWc, wc = w % nWc;
  int l15 = l & 15, lg = l >> 4;
  f32x4 acc[MF][4];
#pragma unroll
  for (int i = 0; i < MF; i++)
#pragma unroll
    for (int j = 0; j < 4; j++) acc[i][j] = (f32x4){0.f, 0.f, 0.f, 0.f};
  int r_ = tid >> 3;
  int s_ = tid & 7;

  auto STAGE = [&](int k0, int nb) {
#pragma unroll
    for (int i = 0; i < 4; i++) {
      int rr = i * 32 + r_;
      int kq = s_ ^ (rr & 7);
      GLOAD_LDS16(A + (size_t)(bm + rr) * K + k0 + kq * 8, &As[nb][rr * 64 + s_ * 8]);
    }
#pragma unroll
    for (int i = 0; i < BN / 32; i++) {
      int rr = i * 32 + r_;
      int kq = s_ ^ (rr & 7);
      GLOAD_LDS16(Wt + (size_t)(bn + rr) * K + k0 + kq * 8, &Bs[nb][rr * 64 + s_ * 8]);
    }
  };

  STAGE(0, 0);
  __syncthreads();
  int cur = 0;
  for (int k0 = 0; k0 < K; k0 += 64) {
    if (k0 + 64 < K) STAGE(k0 + 64, cur ^ 1);
#pragma unroll
    for (int h = 0; h < 2; h++) {
      short8 af[MF], bfr[4];
#pragma unroll
      for (int i = 0; i < MF; i++) {
        int row = wr * (16 * MF) + i * 16 + l15;
        int c = h * 4 + lg;
        af[i] = *(const short8*)&As[cur][row * 64 + ((c ^ (row & 7)) << 3)];
      }
#pragma unroll
      for (int j = 0; j < 4; j++) {
        int row = wc * 64 + j * 16 + l15;
        int c = h * 4 + lg;
        bfr[j] = *(const short8*)&Bs[cur][row * 64 + ((c ^ (row & 7)) << 3)];
      }
#pragma unroll
      for (int i = 0; i < MF; i++)
#pragma unroll
        for (int j = 0; j < 4; j++)
          acc[i][j] = __builtin_amdgcn_mfma_f32_16x16x32_bf16(af[i], bfr[j], acc[i][j], 0, 0, 0);
    }
    __syncthreads();
    cur ^= 1;
  }
  int rb = lg * 4, cb2 = l15;
#pragma unroll
  for (int i = 0; i < MF; i++)
#pragma unroll
    for (int j = 0; j < 4; j++) {
      int gr = bm + wr * (16 * MF) + i * 16 + rb;
      int gc = bn + wc * 64 + j * 16 + cb2;
#pragma unroll
      for (int reg = 0; reg < 4; reg++) {
        float v = acc[i][j][reg];
        size_t idx = (size_t)(gr + reg) * N + gc;
        if (mode == 0) {
          Cf[idx] = v;
        } else if (mode == 1) {
          v = fmaxf(v, 0.f);
          Cb[idx] = __float2bfloat16(v * v);
        } else if (mode == 2) {
          Cb[idx] = __float2bfloat16(v);
        } else {
          Cf[idx] = baseb[idx] + scale[gc] * v;
        }
      }
    }
}

// ---------------- 64x64 tile bf16 GEMM, BK=64, 2-buffer ----------------
// mode 0: f32 out; 2: bf16 out; 3: f32 = base + scale[col]*acc. Grid = 64*(N/64); M=4096.
__global__ __launch_bounds__(256) void gemm64(
    const unsigned short* __restrict__ A, const unsigned short* __restrict__ Wt,
    float* __restrict__ Cf, __hip_bfloat16* __restrict__ Cbo,
    const float* __restrict__ baseb, const float* __restrict__ scale,
    int N, int K, int mode) {
  __shared__ unsigned short As[2][64 * 64];
  __shared__ unsigned short Bs[2][64 * 64];
  int lid = blockIdx.x;
  int x = lid & 7, r = lid >> 3;
  int bm = (x * 8 + (r & 7)) * 64;
  int bn = (r >> 3) * 64;
  int tid = threadIdx.x;
  int w = tid >> 6, l = tid & 63;
  int l15 = l & 15, lg = l >> 4;
  f32x4 acc[4];
#pragma unroll
  for (int j = 0; j < 4; j++) acc[j] = (f32x4){0.f, 0.f, 0.f, 0.f};
  int r_ = tid >> 3;
  int s_ = tid & 7;

  auto STAGE = [&](int k0, int nb) {
#pragma unroll
    for (int i = 0; i < 2; i++) {
      int row = i * 32 + r_;
      int kq = s_ ^ (row & 7);
      GLOAD_LDS16(A + (size_t)(bm + row) * K + k0 + kq * 8, &As[nb][row * 64 + s_ * 8]);
    }
#pragma unroll
    for (int i = 0; i < 2; i++) {
      int row = i * 32 + r_;
      int kq = s_ ^ (row & 7);
      GLOAD_LDS16(Wt + (size_t)(bn + row) * K + k0 + kq * 8, &Bs[nb][row * 64 + s_ * 8]);
    }
  };

  STAGE(0, 0);
  __syncthreads();
  int cur = 0;
  for (int k0 = 0; k0 < K; k0 += 64) {
    if (k0 + 64 < K) STAGE(k0 + 64, cur ^ 1);
#pragma unroll
    for (int h = 0; h < 2; h++) {
      int c = h * 4 + lg;
      int arow = w * 16 + l15;
      short8 af = *(const short8*)&As[cur][arow * 64 + ((c ^ (arow & 7)) << 3)];
#pragma unroll
      for (int j = 0; j < 4; j++) {
        int brow = j * 16 + l15;
        short8 bfr = *(const short8*)&Bs[cur][brow * 64 + ((c ^ (brow & 7)) << 3)];
        acc[j] = __builtin_amdgcn_mfma_f32_16x16x32_bf16(af, bfr, acc[j], 0, 0, 0);
      }
    }
    __syncthreads();
    cur ^= 1;
  }
#pragma unroll
  for (int j = 0; j < 4; j++) {
    int gr = bm + w * 16 + lg * 4;
    int gc = bn + j * 16 + l15;
#pragma unroll
    for (int reg = 0; reg < 4; reg++) {
      float v = acc[j][reg];
      size_t idx = (size_t)(gr + reg) * N + gc;
      if (mode == 0)      Cf[idx] = v;
      else if (mode == 2) Cbo[idx] = __float2bfloat16(v);
      else                Cf[idx] = baseb[idx] + scale[gc] * v;
    }
  }
}

// ---------------- mix + rmsnorm ----------------
__global__ __launch_bounds__(256) void mix_rms_kernel(
    const float* __restrict__ a, const float* __restrict__ b2,
    const float* __restrict__ mix, float* __restrict__ xout,
    __hip_bfloat16* __restrict__ nbf, __hip_bfloat16* __restrict__ rawbf) {
  int row = blockIdx.x;
  size_t base = (size_t)row * D_;
  float v[4]; float ss = 0.f;
#pragma unroll
  for (int i = 0; i < 4; i++) {
    int d = threadIdx.x + i * 256;
    float val = mix[d] * a[base + d] + mix[D_ + d] * b2[base + d];
    v[i] = val; ss += val * val;
  }
  for (int o = 32; o > 0; o >>= 1) ss += __shfl_down(ss, o, 64);
  __shared__ float red[4];
  if ((threadIdx.x & 63) == 0) red[threadIdx.x >> 6] = ss;
  __syncthreads();
  float inv = rsqrtf((red[0] + red[1] + red[2] + red[3]) * (1.f / D_) + RMS_EPS_);
#pragma unroll
  for (int i = 0; i < 4; i++) {
    int d = threadIdx.x + i * 256;
    xout[base + d] = v[i];
    nbf[base + d] = __float2bfloat16(v[i] * inv);
    if (rawbf) rawbf[base + d] = __float2bfloat16(v[i]);
  }
}

__global__ __launch_bounds__(256) void rms_kernel(
    const float* __restrict__ a, __hip_bfloat16* __restrict__ nbf) {
  int row = blockIdx.x;
  size_t base = (size_t)row * D_;
  float v[4]; float ss = 0.f;
#pragma unroll
  for (int i = 0; i < 4; i++) {
    int d = threadIdx.x + i * 256;
    float val = a[base + d];
    v[i] = val; ss += val * val;
  }
  for (int o = 32; o > 0; o >>= 1) ss += __shfl_down(ss, o, 64);
  __shared__ float red[4];
  if ((threadIdx.x & 63) == 0) red[threadIdx.x >> 6] = ss;
  __syncthreads();
  float inv = rsqrtf((red[0] + red[1] + red[2] + red[3]) * (1.f / D_) + RMS_EPS_);
#pragma unroll
  for (int i = 0; i < 4; i++) {
    int d = threadIdx.x + i * 256;
    nbf[base + d] = __float2bfloat16(v[i] * inv);
  }
}

// ---------------- FUSED conv+SiLU + scanA1(states) + scanA2(y_diag) ----------------
// LDS 41 KB -> 3 blocks/CU. C/CBL in bf16 [64][66]; Bs f32 padded [64][65].
__global__ __launch_bounds__(256) void scanAF_kernel(
    const __hip_bfloat16* __restrict__ vg, const __hip_bfloat16* __restrict__ BCm,
    const float* __restrict__ cw, const float* __restrict__ cbias,
    const float* __restrict__ dt_bias, const float* __restrict__ A_log,
    const float* __restrict__ D_param, float* __restrict__ st, float* __restrict__ y) {
  __shared__ __align__(16) float sm[10496];          // 41984 B
  unsigned short* Xh  = (unsigned short*)sm;         // [64][128] bf16 conv output (16384 B)
  unsigned short* Cbh = (unsigned short*)(sm + 4096); // [64][66] bf16 C then CBL (8448 B)
  float* Bs = sm + 6208;                             // [64][65] f32 (16640 B)
  unsigned short* Vg = (unsigned short*)(sm + 6208); // [67][128] bf16 input tile (17152 B, overlays Bs)
  int blk = blockIdx.x;
  int c = blk & 31, h = (blk >> 5) & 15, b = blk >> 9;
  float dt = log1pf(__expf(dt_bias[h]));
  float adt = -__expf(A_log[h]) * dt;
  float Dp = D_param[h];
  int tid = threadIdx.x;
  int l0 = c * 64;
  size_t rBC = ((size_t)(b * L_ + l0)) * 2048 + h * NS_;
  // stage C (bf16 copy) and Vg (67 halo rows)
#pragma unroll
  for (int i = 0; i < 16; i++) {
    int e = tid + i * 256;
    int t = e >> 6, n = e & 63;
    Cbh[t * 66 + n] = *(const unsigned short*)&BCm[rBC + 1024 + (size_t)t * 2048 + n];
  }
  for (int k = 0; k < 5; k++) {
    int e = tid + k * 256;
    if (e < 1072) {
      int rr = e >> 4, s = e & 15;
      int gl = l0 - 3 + rr;
      short8 v;
      if (gl < 0) v = (short8){0, 0, 0, 0, 0, 0, 0, 0};
      else v = *(const short8*)((const unsigned short*)vg +
                ((size_t)(b * L_ + gl)) * 4096 + h * PS_ + s * 8);
      *(short8*)&Vg[rr * 128 + s * 8] = v;
    }
  }
  __syncthreads();
  // conv (4 taps) + SiLU -> Xh bf16
  {
    int p4 = (tid & 31) * 4;
    int t0 = (tid >> 5) * 8;
    float w0[4], w1[4], w2[4], w3[4], bb[4];
#pragma unroll
    for (int q = 0; q < 4; q++) {
      int ch = h * PS_ + p4 + q;
      w0[q] = cw[ch * 4 + 0]; w1[q] = cw[ch * 4 + 1];
      w2[q] = cw[ch * 4 + 2]; w3[q] = cw[ch * 4 + 3];
      bb[q] = cbias[ch];
    }
#pragma unroll
    for (int i = 0; i < 8; i++) {
      int t = t0 + i;
      short4v r0 = *(const short4v*)&Vg[(t + 0) * 128 + p4];
      short4v r1 = *(const short4v*)&Vg[(t + 1) * 128 + p4];
      short4v r2 = *(const short4v*)&Vg[(t + 2) * 128 + p4];
      short4v r3 = *(const short4v*)&Vg[(t + 3) * 128 + p4];
      short4v o;
#pragma unroll
      for (int q = 0; q < 4; q++) {
        float a = bb[q] + w0[q] * b2f((unsigned short)r0[q])
                        + w1[q] * b2f((unsigned short)r1[q])
                        + w2[q] * b2f((unsigned short)r2[q])
                        + w3[q] * b2f((unsigned short)r3[q]);
        float sv = a / (1.f + __expf(-a));
        __hip_bfloat16 hv = __float2bfloat16(sv);
        o[q] = *(short*)&hv;
      }
      *(short4v*)&Xh[t * 128 + p4] = o;
    }
  }
  __syncthreads();                 // Vg reads done; Xh ready
  // stage B (f32, padded 65) over Vg region
#pragma unroll
  for (int i = 0; i < 16; i++) {
    int e = tid + i * 256;
    int t = e >> 6, n = e & 63;
    Bs[t * 65 + n] = __bfloat162float(BCm[rBC + (size_t)t * 2048 + n]);
  }
  __syncthreads();
  // CBL = (C . B) * decay, causal -> bf16 back into Cbh
  int q_ = tid >> 2;
  int kb = (tid & 3) << 4;
  float cbl[16];
#pragma unroll
  for (int kk = 0; kk < 16; kk++) {
    int k = kb + kk;
    float a = 0.f;
    if (k <= q_) {
      for (int n = 0; n < 64; n++) a += b2f(Cbh[q_ * 66 + n]) * Bs[k * 65 + n];
      a *= __expf(adt * (float)(q_ - k));
    }
    cbl[kk] = a;
  }
  __syncthreads();
#pragma unroll
  for (int kk = 0; kk < 16; kk++) {
    __hip_bfloat16 hv = __float2bfloat16(cbl[kk]);
    Cbh[q_ * 66 + kb + kk] = *(unsigned short*)&hv;
  }
  __syncthreads();
  // merged A1 (states) + A2 (y_diag) pass over Xh
  int pg = tid & 31;
  int ng = (tid >> 5) << 3;
  float acc1[8][4], acc2[8][4];
#pragma unroll
  for (int nn = 0; nn < 8; nn++)
#pragma unroll
    for (int i = 0; i < 4; i++) { acc1[nn][i] = 0.f; acc2[nn][i] = 0.f; }
  for (int t = 0; t < 64; t++) {
    short4v xr = *(const short4v*)&Xh[t * 128 + pg * 4];
    float x0 = b2f((unsigned short)xr[0]), x1 = b2f((unsigned short)xr[1]);
    float x2 = b2f((unsigned short)xr[2]), x3 = b2f((unsigned short)xr[3]);
    float dr = __expf(adt * (float)(63 - t));
    float xd0 = x0 * dr, xd1 = x1 * dr, xd2 = x2 * dr, xd3 = x3 * dr;
#pragma unroll
    for (int nn = 0; nn < 8; nn++) {
      float bv = Bs[t * 65 + ng + nn];
      acc1[nn][0] += bv * xd0; acc1[nn][1] += bv * xd1;
      acc1[nn][2] += bv * xd2; acc1[nn][3] += bv * xd3;
      float cv = b2f(Cbh[(ng + nn) * 66 + t]);
      acc2[nn][0] += cv * x0; acc2[nn][1] += cv * x1;
      acc2[nn][2] += cv * x2; acc2[nn][3] += cv * x3;
    }
  }
  size_t sb = ((size_t)((b * HS_ + h) * NC_ + c)) * (NS_ * PS_);
#pragma unroll
  for (int nn = 0; nn < 8; nn++) {
    *(float4*)&st[sb + (size_t)(ng + nn) * PS_ + pg * 4] =
        make_float4(acc1[nn][0] * dt, acc1[nn][1] * dt, acc1[nn][2] * dt, acc1[nn][3] * dt);
  }
#pragma unroll
  for (int qq = 0; qq < 8; qq++) {
    int qr = ng + qq;
    short4v xr = *(const short4v*)&Xh[qr * 128 + pg * 4];
    size_t yo = ((size_t)(b * L_ + l0 + qr)) * DI_ + h * PS_ + pg * 4;
    *(float4*)&y[yo] = make_float4(
        acc2[qq][0] * dt + Dp * b2f((unsigned short)xr[0]),
        acc2[qq][1] * dt + Dp * b2f((unsigned short)xr[1]),
        acc2[qq][2] * dt + Dp * b2f((unsigned short)xr[2]),
        acc2[qq][3] * dt + Dp * b2f((unsigned short)xr[3]));
  }
}

// ---------------- scan pass B1: inter-chunk recurrence, 128 blocks ----------------
__global__ __launch_bounds__(256) void scanB1_kernel(
    float* __restrict__ st, const float* __restrict__ dt_bias,
    const float* __restrict__ A_log) {
  int slice = blockIdx.x & 3;
  int h = (blockIdx.x >> 2) & 15, b = blockIdx.x >> 6;
  float dt = log1pf(__expf(dt_bias[h]));
  float adt = -__expf(A_log[h]) * dt;
  float cdec = __expf(adt * 64.f);
  size_t base = ((size_t)(b * HS_ + h)) * NC_ * (NS_ * PS_) + slice * 2048 + threadIdx.x;
  float hreg[8];
#pragma unroll
  for (int j = 0; j < 8; j++) hreg[j] = 0.f;
  for (int c = 0; c < NC_; c++) {
    size_t o = base + (size_t)c * (NS_ * PS_);
#pragma unroll
    for (int j = 0; j < 8; j++) {
      float tmp = st[o + (size_t)j * 256];
      st[o + (size_t)j * 256] = hreg[j];
      hreg[j] = cdec * hreg[j] + tmp;
    }
  }
}

// ---------------- scan pass B2: y_off + gate SiLU -> bf16; C at +1024 ----------------
__global__ __launch_bounds__(256) void scanB2_kernel(
    const __hip_bfloat16* __restrict__ BCm, const float* __restrict__ st,
    const __hip_bfloat16* __restrict__ vg, const float* __restrict__ dt_bias,
    const float* __restrict__ A_log, const float* __restrict__ y,
    __hip_bfloat16* __restrict__ yout) {
  __shared__ float Cs[64 * 64];
  __shared__ __align__(16) float Hs[64 * 128];
  int blk = blockIdx.x;
  int c = blk & 31, h = (blk >> 5) & 15, b = blk >> 9;
  float dt = log1pf(__expf(dt_bias[h]));
  float adt = -__expf(A_log[h]) * dt;
  int tid = threadIdx.x;
  int l0 = c * 64;
  size_t rC = ((size_t)(b * L_ + l0)) * 2048 + 1024 + h * NS_;
#pragma unroll
  for (int i = 0; i < 16; i++) {
    int e = tid + i * 256;
    int t = e >> 6, n = e & 63;
    Cs[t * 64 + n] = __bfloat162float(BCm[rC + (size_t)t * 2048 + n]);
  }
  size_t sb = ((size_t)((b * HS_ + h) * NC_ + c)) * (NS_ * PS_);
#pragma unroll
  for (int i = 0; i < 32; i++) {
    int e = tid + i * 256;
    Hs[e] = st[sb + e];
  }
  __syncthreads();
  int pg = tid & 31;
  int tg = (tid >> 5) << 3;
  float acc[8][4];
#pragma unroll
  for (int tt = 0; tt < 8; tt++)
#pragma unroll
    for (int i = 0; i < 4; i++) acc[tt][i] = 0.f;
  for (int n = 0; n < 64; n++) {
    float4 h4 = *(const float4*)&Hs[n * 128 + pg * 4];
#pragma unroll
    for (int tt = 0; tt < 8; tt++) {
      float cv = Cs[(tg + tt) * 64 + n];
      acc[tt][0] += cv * h4.x; acc[tt][1] += cv * h4.y;
      acc[tt][2] += cv * h4.z; acc[tt][3] += cv * h4.w;
    }
  }
#pragma unroll
  for (int tt = 0; tt < 8; tt++) {
    int t = tg + tt;
    float dout = __expf(adt * (float)(t + 1));
    size_t row = (size_t)(b * L_ + l0 + t);
#pragma unroll
    for (int i = 0; i < 4; i++) {
      int p = pg * 4 + i;
      float g = __bfloat162float(vg[row * 4096 + 2048 + h * PS_ + p]);
      float yv = y[row * DI_ + h * PS_ + p] + acc[tt][i] * dout;
      yout[row * DI_ + h * PS_ + p] = __float2bfloat16(yv * (g / (1.f + __expf(-g))));
    }
  }
}

// ---------------- rope tables ----------------
__global__ void rope_fill_kernel(float* __restrict__ cosb, float* __restrict__ sinb) {
  int idx = blockIdx.x * 256 + threadIdx.x;
  int i = idx & 31, l = idx >> 5;
  float inv = __expf(-(2.0f * (float)i / (float)PA_) * logf(10000.0f));
  float ang = (float)l * inv;
  cosb[idx] = cosf(ang);
  sinb[idx] = sinf(ang);
}

// ---------------- per-head rmsnorm + rope (+gain), bf16 strided src -> packed bf16 dst ----------------
__global__ __launch_bounds__(256) void qknorm_rope_bf16_kernel(
    const __hip_bfloat16* __restrict__ src, int srcstride, int srcofs,
    __hip_bfloat16* __restrict__ dst, int nh,
    const float* __restrict__ cosb, const float* __restrict__ sinb,
    const float* __restrict__ gain) {
  int row = blockIdx.x * 4 + (threadIdx.x >> 6);
  int lane = threadIdx.x & 63;
  int h = row % nh;
  int tok = row / nh;
  int l = tok & (L_ - 1);
  float v = __bfloat162float(src[(size_t)tok * srcstride + srcofs + h * 64 + lane]);
  float ss = v * v;
  for (int o = 32; o > 0; o >>= 1) ss += __shfl_xor(ss, o, 64);
  v *= rsqrtf(ss * (1.f / PA_) + RMS_EPS_);
  float partner = __shfl_xor(v, 32, 64);
  int i = lane & 31;
  float cth = cosb[l * 32 + i], sth = sinb[l * 32 + i];
  float out = (lane < 32) ? (v * cth + partner * sth) : (v * cth - partner * sth);
  if (gain) out *= gain[h];
  dst[(size_t)tok * (nh * 64) + h * 64 + lane] = __float2bfloat16(out);
}

// ---------------- causal GQA flash attention, bf16 MFMA ----------------
__global__ __launch_bounds__(256) void attn_mfma_kernel(
    const unsigned short* __restrict__ qb, const unsigned short* __restrict__ kb,
    const unsigned short* __restrict__ vt, const float* __restrict__ qgain,
    __hip_bfloat16* __restrict__ ao) {
  __shared__ unsigned short Ks[64][72];
  __shared__ unsigned short Vs[64][72];
  __shared__ unsigned short Psm[4][16][72];
  int blk = blockIdx.x;
  int qi = blk & 15;
  int h  = (blk >> 4) & 15;
  int b  = blk >> 8;
  int hk = h >> 2;
  int tid = threadIdx.x;
  int w = tid >> 6, l = tid & 63;
  int l15 = l & 15, lg = l >> 4;
  int r0 = tid >> 3, s0 = tid & 7;
  float mstat = 8.0f * fabsf(qgain[h]);
  const unsigned short* kbase = kb + (size_t)b * L_ * (HKV_ * PA_) + hk * PA_ + s0 * 8;
  const unsigned short* vbase = vt + ((size_t)(b * HKV_ + hk) * PA_) * L_ + s0 * 8;

  for (int pass = 0; pass < 2; pass++) {
    int qt = pass ? (31 - qi) : qi;
    int q0 = qt * 64;
    int qw = q0 + w * 16;
    short8 qf[2];
    {
      size_t qrow = ((size_t)(b * L_ + qw + l15)) * (HA_ * PA_) + h * PA_;
      qf[0] = *(const short8*)&qb[qrow + lg * 8];
      qf[1] = *(const short8*)&qb[qrow + 32 + lg * 8];
    }
    f32x4 o_acc[4];
#pragma unroll
    for (int db = 0; db < 4; db++) o_acc[db] = (f32x4){0.f, 0.f, 0.f, 0.f};
    f32x4 lsum = (f32x4){0.f, 0.f, 0.f, 0.f};
    int nkt = qt + 1;
    short8 kr0 = *(const short8*)&kbase[(size_t)r0 * (HKV_ * PA_)];
    short8 kr1 = *(const short8*)&kbase[(size_t)(r0 + 32) * (HKV_ * PA_)];
    short8 vr0 = *(const short8*)&vbase[(size_t)r0 * L_];
    short8 vr1 = *(const short8*)&vbase[(size_t)(r0 + 32) * L_];
    for (int kt = 0; kt < nkt; kt++) {
      int k0 = kt * 64;
      __syncthreads();
      *(short8*)&Ks[r0][s0 * 8] = kr0;
      *(short8*)&Ks[r0 + 32][s0 * 8] = kr1;
      *(short8*)&Vs[r0][s0 * 8] = vr0;
      *(short8*)&Vs[r0 + 32][s0 * 8] = vr1;
      if (kt + 1 < nkt) {
        int k1 = k0 + 64;
        kr0 = *(const short8*)&kbase[(size_t)(k1 + r0) * (HKV_ * PA_)];
        kr1 = *(const short8*)&kbase[(size_t)(k1 + r0 + 32) * (HKV_ * PA_)];
        vr0 = *(const short8*)&vbase[(size_t)r0 * L_ + k1];
        vr1 = *(const short8*)&vbase[(size_t)(r0 + 32) * L_ + k1];
      }
      __syncthreads();
      f32x4 s_acc[4];
#pragma unroll
      for (int kb2 = 0; kb2 < 4; kb2++) {
        short8 b0 = *(const short8*)&Ks[kb2 * 16 + l15][lg * 8];
        short8 b1 = *(const short8*)&Ks[kb2 * 16 + l15][32 + lg * 8];
        f32x4 s = (f32x4){0.f, 0.f, 0.f, 0.f};
        s = __builtin_amdgcn_mfma_f32_16x16x32_bf16(qf[0], b0, s, 0, 0, 0);
        s = __builtin_amdgcn_mfma_f32_16x16x32_bf16(qf[1], b1, s, 0, 0, 0);
        s_acc[kb2] = s;
      }
      bool diag = (kt == qt);
#pragma unroll
      for (int kb2 = 0; kb2 < 4; kb2++) {
        int key = k0 + kb2 * 16 + l15;
#pragma unroll
        for (int reg = 0; reg < 4; reg++) {
          float p = __expf(s_acc[kb2][reg] * 0.125f - mstat);
          if (diag && key > qw + lg * 4 + reg) p = 0.f;
          lsum[reg] += p;
          __hip_bfloat16 hv = __float2bfloat16(p);
          Psm[w][lg * 4 + reg][kb2 * 16 + l15] = *(unsigned short*)&hv;
        }
      }
      asm volatile("s_waitcnt lgkmcnt(0)" ::: "memory");
#pragma unroll
      for (int ks = 0; ks < 2; ks++) {
        short8 pa = *(const short8*)&Psm[w][l15][ks * 32 + lg * 8];
#pragma unroll
        for (int db = 0; db < 4; db++) {
          short8 vb8 = *(const short8*)&Vs[db * 16 + l15][ks * 32 + lg * 8];
          o_acc[db] = __builtin_amdgcn_mfma_f32_16x16x32_bf16(pa, vb8, o_acc[db], 0, 0, 0);
        }
      }
    }
#pragma unroll
    for (int of = 1; of < 16; of <<= 1) {
      lsum[0] += __shfl_xor(lsum[0], of, 64);
      lsum[1] += __shfl_xor(lsum[1], of, 64);
      lsum[2] += __shfl_xor(lsum[2], of, 64);
      lsum[3] += __shfl_xor(lsum[3], of, 64);
    }
#pragma unroll
    for (int reg = 0; reg < 4; reg++) {
      float invl = 1.0f / lsum[reg];
      size_t row = (size_t)(b * L_ + qw + lg * 4 + reg);
#pragma unroll
      for (int db = 0; db < 4; db++)
        ao[row * D_ + h * PA_ + db * 16 + l15] = __float2bfloat16(o_acc[db][reg] * invl);
    }
  }
}

// ---------------- host ----------------
extern "C" void kernel_launch(void* const* d_in, const int* in_sizes, int n_in,
                              void* d_out, int out_size, void* d_ws, size_t ws_size,
                              hipStream_t stream) {
  (void)in_sizes; (void)n_in; (void)out_size; (void)ws_size;
  const float* x           = (const float*)d_in[0];
  const float* in_proj_w   = (const float*)d_in[1];
  const float* conv_w      = (const float*)d_in[2];
  const float* conv_b      = (const float*)d_in[3];
  const float* B_proj_w    = (const float*)d_in[4];
  const float* C_proj_w    = (const float*)d_in[5];
  const float* dt_bias     = (const float*)d_in[6];
  const float* A_log       = (const float*)d_in[7];
  const float* D_param     = (const float*)d_in[8];
  const float* out_proj_w  = (const float*)d_in[9];
  const float* resid_mix_m = (const float*)d_in[10];
  const float* mamba_scale = (const float*)d_in[11];
  const float* m_fc_w      = (const float*)d_in[12];
  const float* m_proj_w    = (const float*)d_in[13];
  const float* m_mlp_scale = (const float*)d_in[14];
  const float* resid_mix_a = (const float*)d_in[15];
  const float* q_w         = (const float*)d_in[16];
  const float* k_w         = (const float*)d_in[17];
  const float* v_w         = (const float*)d_in[18];
  const float* o_w         = (const float*)d_in[19];
  const float* q_gain      = (const float*)d_in[20];
  const float* attn_scale  = (const float*)d_in[21];
  const float* a_fc_w      = (const float*)d_in[22];
  const float* a_proj_w    = (const float*)d_in[23];
  const float* a_mlp_scale = (const float*)d_in[24];
  float* ws  = (float*)d_ws;
  float* out = (float*)d_out;

  // ---- workspace layout (float units) ----
  float* xm    = ws;
  float* vgR   = ws + 4194304;
  float* xvR   = ws + 12582912;
  float* stR   = ws + 20971520;
  float* nbR   = ws + 29360128;
  float* xmbR  = ws + 31457280;
  float* BCR   = ws + 33554432;
  float* WtR   = ws + 37748736;
  float* cosb  = ws + 51642368;
  float* sinb  = cosb + 65536;

  __hip_bfloat16* vg   = (__hip_bfloat16*)vgR;      // [NT][4096] bf16 (value|gate)
  __hip_bfloat16* qkvb = (__hip_bfloat16*)vgR;      // [NT][1536] bf16 (attn phase)
  float*          yv   = xvR;                       // y f32 [NT][2048]
  float*          st   = stR;
  __hip_bfloat16* hb   = (__hip_bfloat16*)stR;
  __hip_bfloat16* nbb  = (__hip_bfloat16*)nbR;
  __hip_bfloat16* xmb  = (__hip_bfloat16*)xmbR;
  __hip_bfloat16* ybb  = (__hip_bfloat16*)nbR;
  __hip_bfloat16* BCm  = (__hip_bfloat16*)BCR;
  __hip_bfloat16* qbb  = (__hip_bfloat16*)xvR;                 // [NT][1024]
  __hip_bfloat16* kbb  = (__hip_bfloat16*)(xvR + 2097152);     // [NT][256]
  __hip_bfloat16* vtb  = (__hip_bfloat16*)(xvR + 2621440);     // [2][256][2048]
  __hip_bfloat16* aob  = (__hip_bfloat16*)(xvR + 3145728);     // [NT][1024]

  __hip_bfloat16* Wt = (__hip_bfloat16*)WtR;
  size_t o_in  = 0;
  size_t o_B   = o_in  + (size_t)4096 * 1024;
  size_t o_out = o_B   + (size_t)2048 * 1024;
  size_t o_mfc = o_out + (size_t)1024 * 2048;
  size_t o_mpj = o_mfc + (size_t)4096 * 1024;
  size_t o_qkv = o_mpj + (size_t)1024 * 4096;
  size_t o_o   = o_qkv + (size_t)1536 * 1024;
  size_t o_afc = o_o   + (size_t)1024 * 1024;
  size_t o_apj = o_afc + (size_t)4096 * 1024;

#define TCVT(Wp, off, K, N) \
  transpose_cvt<<<dim3((N) / 32, (K) / 32), 256, 0, stream>>>((Wp), Wt + (off), (K), (N), (N))
  TCVT(in_proj_w,  o_in,  1024, 4096);
  TCVT(B_proj_w,   o_B,   1024, 1024);
  TCVT(C_proj_w,   o_B + (size_t)1024 * 1024, 1024, 1024);
  TCVT(out_proj_w, o_out, 2048, 1024);
  TCVT(m_fc_w,     o_mfc, 1024, 4096);
  TCVT(m_proj_w,   o_mpj, 4096, 1024);
  TCVT(q_w,        o_qkv, 1024, 1024);
  TCVT(k_w,        o_qkv + (size_t)1024 * 1024, 1024, 256);
  TCVT(v_w,        o_qkv + (size_t)1280 * 1024, 1024, 256);
  TCVT(o_w,        o_o,   1024, 1024);
  TCVT(a_fc_w,     o_afc, 1024, 4096);
  TCVT(a_proj_w,   o_apj, 4096, 1024);
#undef TCVT

#define GEMM(BN, Abuf, Woff, Cfp, Cbp, basep, scalep, N, K, mode, rsh) \
  gemm_bf16_t<BN><<<32 * ((N) / (BN)), 256, 0, stream>>>( \
      (const unsigned short*)(Abuf), (const unsigned short*)(Wt + (Woff)), \
      (Cfp), (Cbp), (basep), (scalep), (N), (K), (N) / (BN), (mode), (rsh))
#define GEMM64(Abuf, Woff, Cfp, Cbop, basep, scalep, N, K, mode) \
  gemm64<<<64 * ((N) / 64), 256, 0, stream>>>( \
      (const unsigned short*)(Abuf), (const unsigned short*)(Wt + (Woff)), \
      (Cfp), (Cbop), (basep), (scalep), (N), (K), (mode))
#define GEMM256(MODE, Abuf, Woff, Cbp) \
  gemm256_k32<MODE><<<256, 512, 0, stream>>>( \
      (const unsigned short*)(Abuf), (const unsigned short*)(Wt + (Woff)), \
      (Cbp), 4096, 1024)

  // --- mamba branch ---
  mix_rms_kernel<<<NT_, 256, 0, stream>>>(x, x, resid_mix_m, xm, nbb, xmb);
  GEMM256(2, nbb, o_in, vg);
  GEMM(128, xmb, o_B, (float*)0, BCm, (const float*)0, (const float*)0, 2048, 1024, 2, 0);
  scanAF_kernel<<<B_ * HS_ * NC_, 256, 0, stream>>>(vg, BCm, conv_w, conv_b,
                                                    dt_bias, A_log, D_param, st, yv);
  scanB1_kernel<<<B_ * HS_ * 4, 256, 0, stream>>>(st, dt_bias, A_log);
  scanB2_kernel<<<B_ * HS_ * NC_, 256, 0, stream>>>(BCm, st, vg, dt_bias, A_log, yv, ybb);
  GEMM64(ybb, o_out, xm, (__hip_bfloat16*)0, xm, mamba_scale, 1024, 2048, 3);
  // --- mamba MLP ---
  rms_kernel<<<NT_, 256, 0, stream>>>(xm, nbb);
  GEMM256(1, nbb, o_mfc, hb);
  GEMM64(hb, o_mpj, xm, (__hip_bfloat16*)0, xm, m_mlp_scale, 1024, 4096, 3);
  // --- attention branch ---
  mix_rms_kernel<<<NT_, 256, 0, stream>>>(xm, x, resid_mix_a, xm, nbb, (__hip_bfloat16*)0);
  GEMM64(nbb, o_qkv, (float*)0, qkvb, (const float*)0, (const float*)0, 1536, 1024, 2);
  rope_fill_kernel<<<L_ * 32 / 256, 256, 0, stream>>>(cosb, sinb);
  qknorm_rope_bf16_kernel<<<NT_ * HA_ / 4, 256, 0, stream>>>(qkvb, 1536, 0, qbb, HA_, cosb, sinb, q_gain);
  qknorm_rope_bf16_kernel<<<NT_ * HKV_ / 4, 256, 0, stream>>>(qkvb, 1536, 1024, kbb, HKV_, cosb, sinb, (const float*)0);
  transpose_bf16<<<dim3(256 / 32, 2048 / 32), 256, 0, stream>>>(
      (const unsigned short*)qkvb + 1280, (unsigned short*)vtb, 2048, 256, 1536);
  transpose_bf16<<<dim3(256 / 32, 2048 / 32), 256, 0, stream>>>(
      (const unsigned short*)qkvb + (size_t)L_ * 1536 + 1280,
      (unsigned short*)vtb + (size_t)256 * L_, 2048, 256, 1536);
  attn_mfma_kernel<<<B_ * HA_ * 16, 256, 0, stream>>>(
      (const unsigned short*)qbb, (const unsigned short*)kbb, (const unsigned short*)vtb,
      q_gain, aob);
  GEMM64(aob, o_o, xm, (__hip_bfloat16*)0, xm, attn_scale, 1024, 1024, 3);
  // --- attention MLP ---
  rms_kernel<<<NT_, 256, 0, stream>>>(xm, nbb);
  GEMM256(1, nbb, o_afc, hb);
  GEMM64(hb, o_apj, out, (__hip_bfloat16*)0, xm, a_mlp_scale, 1024, 4096, 3);
#undef GEMM
#undef GEMM64
#undef GEMM256
}

// Round 16
// 635.652 us; speedup vs baseline: 1.0271x; 1.0271x over previous
//
#include <hip/hip_runtime.h>
#include <hip/hip_bf16.h>
#include <math.h>

#define D_ 1024
#define DI_ 2048
#define HS_ 16
#define PS_ 128
#define NS_ 64
#define HA_ 16
#define HKV_ 4
#define PA_ 64
#define B_ 2
#define L_ 2048
#define NT_ 4096          // B_*L_
#define NC_ 32            // L_/64
#define RMS_EPS_ 1.1920929e-7f

typedef __attribute__((ext_vector_type(8))) short short8;
typedef __attribute__((ext_vector_type(4))) short short4v;
typedef __attribute__((ext_vector_type(4))) float f32x4;

#define GLOAD_LDS16(gp, lp)                                                        \
  __builtin_amdgcn_global_load_lds(                                               \
      (const __attribute__((address_space(1))) unsigned int*)(gp),                \
      (__attribute__((address_space(3))) unsigned int*)(lp), 16, 0, 0)

__device__ __forceinline__ float b2f(unsigned short u) {
  union { unsigned int i; float f; } x;
  x.i = ((unsigned int)u) << 16;
  return x.f;
}

// ---------------- transpose + fp32->bf16: W[K rows x N cols, row-stride ldw] -> Wt[N][K] ----------------
__global__ __launch_bounds__(256) void transpose_cvt(
    const float* __restrict__ W, __hip_bfloat16* __restrict__ Wt, int K, int N, int ldw) {
  __shared__ float t[32][33];
  int n0 = blockIdx.x * 32, k0 = blockIdx.y * 32;
  int tx = threadIdx.x & 31, ty = threadIdx.x >> 5;
#pragma unroll
  for (int i = 0; i < 4; i++)
    t[ty + i * 8][tx] = W[(size_t)(k0 + ty + i * 8) * ldw + n0 + tx];
  __syncthreads();
#pragma unroll
  for (int i = 0; i < 4; i++)
    Wt[(size_t)(n0 + ty + i * 8) * K + k0 + tx] = __float2bfloat16(t[tx][ty + i * 8]);
}

// ---------------- transpose bf16 -> bf16 ----------------
__global__ __launch_bounds__(256) void transpose_bf16(
    const unsigned short* __restrict__ S, unsigned short* __restrict__ D,
    int K, int N, int lds) {
  __shared__ unsigned short t[32][33];
  int n0 = blockIdx.x * 32, k0 = blockIdx.y * 32;
  int tx = threadIdx.x & 31, ty = threadIdx.x >> 5;
#pragma unroll
  for (int i = 0; i < 4; i++)
    t[ty + i * 8][tx] = S[(size_t)(k0 + ty + i * 8) * lds + n0 + tx];
  __syncthreads();
#pragma unroll
  for (int i = 0; i < 4; i++)
    D[(size_t)(n0 + ty + i * 8) * K + k0 + tx] = t[tx][ty + i * 8];
}

// ---------------- 256x256 tile, BK=32, 3-stage pipelined bf16 GEMM (N=4096,K=1024) ----------------
template<int MODE>
__global__ __launch_bounds__(512) void gemm256_k32(
    const unsigned short* __restrict__ A, const unsigned short* __restrict__ Wt,
    __hip_bfloat16* __restrict__ Cb, int N, int K) {
  __shared__ unsigned short As[3][256 * 32];
  __shared__ unsigned short Bs[3][256 * 32];
  int lid = blockIdx.x;
  int x = lid & 7, r = lid >> 3;
  int bm = ((x >> 2) * 8 + (r & 7)) * 256;
  int bn = ((x & 3) * 4 + (r >> 3)) * 256;
  int tid = threadIdx.x;
  int w = tid >> 6, l = tid & 63;
  int wr = w >> 2, wc = w & 3;
  int l15 = l & 15, lg = l >> 4;
  int rr = tid >> 2, ss = tid & 3;

  f32x4 acc[8][4];
#pragma unroll
  for (int i = 0; i < 8; i++)
#pragma unroll
    for (int j = 0; j < 4; j++) acc[i][j] = (f32x4){0.f, 0.f, 0.f, 0.f};

  auto STAGE = [&](int kt, int nb) {
    int k0 = kt * 32;
#pragma unroll
    for (int p = 0; p < 2; p++) {
      int row = p * 128 + rr;
      int kq = ss ^ ((row >> 1) & 3);
      GLOAD_LDS16(A + (size_t)(bm + row) * K + k0 + kq * 8, &As[nb][row * 32 + ss * 8]);
    }
#pragma unroll
    for (int p = 0; p < 2; p++) {
      int row = p * 128 + rr;
      int kq = ss ^ ((row >> 1) & 3);
      GLOAD_LDS16(Wt + (size_t)(bn + row) * K + k0 + kq * 8, &Bs[nb][row * 32 + ss * 8]);
    }
  };

  int KT = K >> 5;
  STAGE(0, 0);
  STAGE(1, 1);
  int buf = 0;
  for (int t = 0; t < KT; ++t) {
    if (t + 1 < KT) {
      asm volatile("s_waitcnt vmcnt(4)" ::: "memory");
    } else {
      asm volatile("s_waitcnt vmcnt(0)" ::: "memory");
    }
    __builtin_amdgcn_s_barrier();
    __builtin_amdgcn_sched_barrier(0);
    if (t + 2 < KT) STAGE(t + 2, (t + 2) % 3);
    short8 bf[4];
#pragma unroll
    for (int j = 0; j < 4; j++) {
      int row = wc * 64 + j * 16 + l15;
      bf[j] = *(const short8*)&Bs[buf][row * 32 + ((lg ^ ((row >> 1) & 3)) << 3)];
    }
#pragma unroll
    for (int i = 0; i < 8; i++) {
      int row = wr * 128 + i * 16 + l15;
      short8 af = *(const short8*)&As[buf][row * 32 + ((lg ^ ((row >> 1) & 3)) << 3)];
#pragma unroll
      for (int j = 0; j < 4; j++)
        acc[i][j] = __builtin_amdgcn_mfma_f32_16x16x32_bf16(af, bf[j], acc[i][j], 0, 0, 0);
    }
    buf = (buf == 2) ? 0 : buf + 1;
  }
#pragma unroll
  for (int i = 0; i < 8; i++)
#pragma unroll
    for (int j = 0; j < 4; j++) {
      int gr = bm + wr * 128 + i * 16 + lg * 4;
      int gc = bn + wc * 64 + j * 16 + l15;
#pragma unroll
      for (int reg = 0; reg < 4; reg++) {
        float v = acc[i][j][reg];
        if (MODE == 1) { v = fmaxf(v, 0.f); v = v * v; }
        Cb[(size_t)(gr + reg) * N + gc] = __float2bfloat16(v);
      }
    }
}

// ---------------- bf16 MFMA GEMM, BK=64 double-buffered, tile 128 x BN (BC proj) ----------------
template<int BN>
__global__ __launch_bounds__(256) void gemm_bf16_t(
    const unsigned short* __restrict__ A, const unsigned short* __restrict__ Wt,
    float* __restrict__ Cf, __hip_bfloat16* __restrict__ Cb,
    const float* __restrict__ baseb, const float* __restrict__ scale,
    int N, int K, int gn, int mode, int rsh) {
  constexpr int nWc = BN / 64;
  constexpr int nWr = 4 / nWc;
  constexpr int MF  = 8 / nWr;
  __shared__ unsigned short As[2][128 * 64];
  __shared__ unsigned short Bs[2][BN * 64];
  int lid = blockIdx.x;
  int x = lid & 7, r = lid >> 3;
  int bm, bn;
  if (rsh == 0) {
    int RN = gn >> 2;
    bm = ((x >> 2) * 16 + (r & 15)) * 128;
    bn = ((x & 3) * RN + (r >> 4)) * BN;
  } else {
    bm = (x * 4 + (r & 3)) * 128;
    bn = (r >> 2) * BN;
  }
  int tid = threadIdx.x;
  int w = tid >> 6, l = tid & 63;
  int wr = w / nWc, wc = w % nWc;
  int l15 = l & 15, lg = l >> 4;
  f32x4 acc[MF][4];
#pragma unroll
  for (int i = 0; i < MF; i++)
#pragma unroll
    for (int j = 0; j < 4; j++) acc[i][j] = (f32x4){0.f, 0.f, 0.f, 0.f};
  int r_ = tid >> 3;
  int s_ = tid & 7;

  auto STAGE = [&](int k0, int nb) {
#pragma unroll
    for (int i = 0; i < 4; i++) {
      int rr = i * 32 + r_;
      int kq = s_ ^ (rr & 7);
      GLOAD_LDS16(A + (size_t)(bm + rr) * K + k0 + kq * 8, &As[nb][rr * 64 + s_ * 8]);
    }
#pragma unroll
    for (int i = 0; i < BN / 32; i++) {
      int rr = i * 32 + r_;
      int kq = s_ ^ (rr & 7);
      GLOAD_LDS16(Wt + (size_t)(bn + rr) * K + k0 + kq * 8, &Bs[nb][rr * 64 + s_ * 8]);
    }
  };

  STAGE(0, 0);
  __syncthreads();
  int cur = 0;
  for (int k0 = 0; k0 < K; k0 += 64) {
    if (k0 + 64 < K) STAGE(k0 + 64, cur ^ 1);
#pragma unroll
    for (int h = 0; h < 2; h++) {
      short8 af[MF], bfr[4];
#pragma unroll
      for (int i = 0; i < MF; i++) {
        int row = wr * (16 * MF) + i * 16 + l15;
        int c = h * 4 + lg;
        af[i] = *(const short8*)&As[cur][row * 64 + ((c ^ (row & 7)) << 3)];
      }
#pragma unroll
      for (int j = 0; j < 4; j++) {
        int row = wc * 64 + j * 16 + l15;
        int c = h * 4 + lg;
        bfr[j] = *(const short8*)&Bs[cur][row * 64 + ((c ^ (row & 7)) << 3)];
      }
#pragma unroll
      for (int i = 0; i < MF; i++)
#pragma unroll
        for (int j = 0; j < 4; j++)
          acc[i][j] = __builtin_amdgcn_mfma_f32_16x16x32_bf16(af[i], bfr[j], acc[i][j], 0, 0, 0);
    }
    __syncthreads();
    cur ^= 1;
  }
  int rb = lg * 4, cb2 = l15;
#pragma unroll
  for (int i = 0; i < MF; i++)
#pragma unroll
    for (int j = 0; j < 4; j++) {
      int gr = bm + wr * (16 * MF) + i * 16 + rb;
      int gc = bn + wc * 64 + j * 16 + cb2;
#pragma unroll
      for (int reg = 0; reg < 4; reg++) {
        float v = acc[i][j][reg];
        size_t idx = (size_t)(gr + reg) * N + gc;
        if (mode == 0) {
          Cf[idx] = v;
        } else if (mode == 1) {
          v = fmaxf(v, 0.f);
          Cb[idx] = __float2bfloat16(v * v);
        } else if (mode == 2) {
          Cb[idx] = __float2bfloat16(v);
        } else {
          Cf[idx] = baseb[idx] + scale[gc] * v;
        }
      }
    }
}

// ---------------- 64x64 tile bf16 GEMM, BK=64, 2-buffer ----------------
// mode 0: f32 out; 2: bf16 out; 3: f32 = base + scale[col]*acc. Grid = 64*(N/64); M=4096.
__global__ __launch_bounds__(256) void gemm64(
    const unsigned short* __restrict__ A, const unsigned short* __restrict__ Wt,
    float* __restrict__ Cf, __hip_bfloat16* __restrict__ Cbo,
    const float* __restrict__ baseb, const float* __restrict__ scale,
    int N, int K, int mode) {
  __shared__ unsigned short As[2][64 * 64];
  __shared__ unsigned short Bs[2][64 * 64];
  int lid = blockIdx.x;
  int x = lid & 7, r = lid >> 3;
  int bm = (x * 8 + (r & 7)) * 64;
  int bn = (r >> 3) * 64;
  int tid = threadIdx.x;
  int w = tid >> 6, l = tid & 63;
  int l15 = l & 15, lg = l >> 4;
  f32x4 acc[4];
#pragma unroll
  for (int j = 0; j < 4; j++) acc[j] = (f32x4){0.f, 0.f, 0.f, 0.f};
  int r_ = tid >> 3;
  int s_ = tid & 7;

  auto STAGE = [&](int k0, int nb) {
#pragma unroll
    for (int i = 0; i < 2; i++) {
      int row = i * 32 + r_;
      int kq = s_ ^ (row & 7);
      GLOAD_LDS16(A + (size_t)(bm + row) * K + k0 + kq * 8, &As[nb][row * 64 + s_ * 8]);
    }
#pragma unroll
    for (int i = 0; i < 2; i++) {
      int row = i * 32 + r_;
      int kq = s_ ^ (row & 7);
      GLOAD_LDS16(Wt + (size_t)(bn + row) * K + k0 + kq * 8, &Bs[nb][row * 64 + s_ * 8]);
    }
  };

  STAGE(0, 0);
  __syncthreads();
  int cur = 0;
  for (int k0 = 0; k0 < K; k0 += 64) {
    if (k0 + 64 < K) STAGE(k0 + 64, cur ^ 1);
#pragma unroll
    for (int h = 0; h < 2; h++) {
      int c = h * 4 + lg;
      int arow = w * 16 + l15;
      short8 af = *(const short8*)&As[cur][arow * 64 + ((c ^ (arow & 7)) << 3)];
#pragma unroll
      for (int j = 0; j < 4; j++) {
        int brow = j * 16 + l15;
        short8 bfr = *(const short8*)&Bs[cur][brow * 64 + ((c ^ (brow & 7)) << 3)];
        acc[j] = __builtin_amdgcn_mfma_f32_16x16x32_bf16(af, bfr, acc[j], 0, 0, 0);
      }
    }
    __syncthreads();
    cur ^= 1;
  }
#pragma unroll
  for (int j = 0; j < 4; j++) {
    int gr = bm + w * 16 + lg * 4;
    int gc = bn + j * 16 + l15;
#pragma unroll
    for (int reg = 0; reg < 4; reg++) {
      float v = acc[j][reg];
      size_t idx = (size_t)(gr + reg) * N + gc;
      if (mode == 0)      Cf[idx] = v;
      else if (mode == 2) Cbo[idx] = __float2bfloat16(v);
      else                Cf[idx] = baseb[idx] + scale[gc] * v;
    }
  }
}

// ---------------- mix + rmsnorm ----------------
__global__ __launch_bounds__(256) void mix_rms_kernel(
    const float* __restrict__ a, const float* __restrict__ b2,
    const float* __restrict__ mix, float* __restrict__ xout,
    __hip_bfloat16* __restrict__ nbf, __hip_bfloat16* __restrict__ rawbf) {
  int row = blockIdx.x;
  size_t base = (size_t)row * D_;
  float v[4]; float ss = 0.f;
#pragma unroll
  for (int i = 0; i < 4; i++) {
    int d = threadIdx.x + i * 256;
    float val = mix[d] * a[base + d] + mix[D_ + d] * b2[base + d];
    v[i] = val; ss += val * val;
  }
  for (int o = 32; o > 0; o >>= 1) ss += __shfl_down(ss, o, 64);
  __shared__ float red[4];
  if ((threadIdx.x & 63) == 0) red[threadIdx.x >> 6] = ss;
  __syncthreads();
  float inv = rsqrtf((red[0] + red[1] + red[2] + red[3]) * (1.f / D_) + RMS_EPS_);
#pragma unroll
  for (int i = 0; i < 4; i++) {
    int d = threadIdx.x + i * 256;
    xout[base + d] = v[i];
    nbf[base + d] = __float2bfloat16(v[i] * inv);
    if (rawbf) rawbf[base + d] = __float2bfloat16(v[i]);
  }
}

__global__ __launch_bounds__(256) void rms_kernel(
    const float* __restrict__ a, __hip_bfloat16* __restrict__ nbf) {
  int row = blockIdx.x;
  size_t base = (size_t)row * D_;
  float v[4]; float ss = 0.f;
#pragma unroll
  for (int i = 0; i < 4; i++) {
    int d = threadIdx.x + i * 256;
    float val = a[base + d];
    v[i] = val; ss += val * val;
  }
  for (int o = 32; o > 0; o >>= 1) ss += __shfl_down(ss, o, 64);
  __shared__ float red[4];
  if ((threadIdx.x & 63) == 0) red[threadIdx.x >> 6] = ss;
  __syncthreads();
  float inv = rsqrtf((red[0] + red[1] + red[2] + red[3]) * (1.f / D_) + RMS_EPS_);
#pragma unroll
  for (int i = 0; i < 4; i++) {
    int d = threadIdx.x + i * 256;
    nbf[base + d] = __float2bfloat16(v[i] * inv);
  }
}

// ---------------- FUSED conv+SiLU + scanA1(states) + scanA2(y_diag) ----------------
// vg bf16 [NT][4096]; BCm bf16 [NT][2048]; writes st f32 and y f32 [NT][2048].
// All-f32 LDS matrices (round-14 structure); Bs padded [64][65] to cut CBL conflicts.
__global__ __launch_bounds__(256) void scanAF_kernel(
    const __hip_bfloat16* __restrict__ vg, const __hip_bfloat16* __restrict__ BCm,
    const float* __restrict__ cw, const float* __restrict__ cbias,
    const float* __restrict__ dt_bias, const float* __restrict__ A_log,
    const float* __restrict__ D_param, float* __restrict__ st, float* __restrict__ y) {
  __shared__ __align__(16) float sm[12544];      // 50176 B
  unsigned short* Xh = (unsigned short*)sm;      // [64][128] bf16 conv output
  float* Cb = sm + 4096;                         // [64][65] f32
  float* Bs = sm + 8256;                         // [64][65] f32 padded (overlays Vg)
  unsigned short* Vg = (unsigned short*)(sm + 8256);  // [67][128] bf16 input tile (4288 floats)
  int blk = blockIdx.x;
  int c = blk & 31, h = (blk >> 5) & 15, b = blk >> 9;
  float dt = log1pf(__expf(dt_bias[h]));
  float adt = -__expf(A_log[h]) * dt;
  float Dp = D_param[h];
  int tid = threadIdx.x;
  int l0 = c * 64;
  size_t rBC = ((size_t)(b * L_ + l0)) * 2048 + h * NS_;
#pragma unroll
  for (int i = 0; i < 16; i++) {
    int e = tid + i * 256;
    int t = e >> 6, n = e & 63;
    Cb[t * 65 + n] = __bfloat162float(BCm[rBC + 1024 + (size_t)t * 2048 + n]);
  }
  for (int k = 0; k < 5; k++) {
    int e = tid + k * 256;
    if (e < 1072) {
      int rr = e >> 4, s = e & 15;
      int gl = l0 - 3 + rr;
      short8 v;
      if (gl < 0) v = (short8){0, 0, 0, 0, 0, 0, 0, 0};
      else v = *(const short8*)((const unsigned short*)vg +
                ((size_t)(b * L_ + gl)) * 4096 + h * PS_ + s * 8);
      *(short8*)&Vg[rr * 128 + s * 8] = v;
    }
  }
  __syncthreads();
  // conv (4 taps) + SiLU -> Xh bf16
  {
    int p4 = (tid & 31) * 4;
    int t0 = (tid >> 5) * 8;
    float w0[4], w1[4], w2[4], w3[4], bb[4];
#pragma unroll
    for (int q = 0; q < 4; q++) {
      int ch = h * PS_ + p4 + q;
      w0[q] = cw[ch * 4 + 0]; w1[q] = cw[ch * 4 + 1];
      w2[q] = cw[ch * 4 + 2]; w3[q] = cw[ch * 4 + 3];
      bb[q] = cbias[ch];
    }
#pragma unroll
    for (int i = 0; i < 8; i++) {
      int t = t0 + i;
      short4v r0 = *(const short4v*)&Vg[(t + 0) * 128 + p4];
      short4v r1 = *(const short4v*)&Vg[(t + 1) * 128 + p4];
      short4v r2 = *(const short4v*)&Vg[(t + 2) * 128 + p4];
      short4v r3 = *(const short4v*)&Vg[(t + 3) * 128 + p4];
      short4v o;
#pragma unroll
      for (int q = 0; q < 4; q++) {
        float a = bb[q] + w0[q] * b2f((unsigned short)r0[q])
                        + w1[q] * b2f((unsigned short)r1[q])
                        + w2[q] * b2f((unsigned short)r2[q])
                        + w3[q] * b2f((unsigned short)r3[q]);
        float sv = a / (1.f + __expf(-a));
        __hip_bfloat16 hv = __float2bfloat16(sv);
        o[q] = *(short*)&hv;
      }
      *(short4v*)&Xh[t * 128 + p4] = o;
    }
  }
  __syncthreads();                 // Vg reads done; Xh ready
  // stage B (f32, padded stride 65) over Vg region
#pragma unroll
  for (int i = 0; i < 16; i++) {
    int e = tid + i * 256;
    int t = e >> 6, n = e & 63;
    Bs[t * 65 + n] = __bfloat162float(BCm[rBC + (size_t)t * 2048 + n]);
  }
  __syncthreads();
  // CBL = (C . B) * decay, causal
  int q_ = tid >> 2;
  int kb = (tid & 3) << 4;
  float cbl[16];
#pragma unroll
  for (int kk = 0; kk < 16; kk++) {
    int k = kb + kk;
    float a = 0.f;
    if (k <= q_) {
      for (int n = 0; n < 64; n++) a += Cb[q_ * 65 + n] * Bs[k * 65 + n];
      a *= __expf(adt * (float)(q_ - k));
    }
    cbl[kk] = a;
  }
  __syncthreads();
#pragma unroll
  for (int kk = 0; kk < 16; kk++) Cb[q_ * 65 + kb + kk] = cbl[kk];
  __syncthreads();
  // merged A1 (states) + A2 (y_diag) pass over Xh
  int pg = tid & 31;
  int ng = (tid >> 5) << 3;
  float acc1[8][4], acc2[8][4];
#pragma unroll
  for (int nn = 0; nn < 8; nn++)
#pragma unroll
    for (int i = 0; i < 4; i++) { acc1[nn][i] = 0.f; acc2[nn][i] = 0.f; }
  for (int t = 0; t < 64; t++) {
    short4v xr = *(const short4v*)&Xh[t * 128 + pg * 4];
    float x0 = b2f((unsigned short)xr[0]), x1 = b2f((unsigned short)xr[1]);
    float x2 = b2f((unsigned short)xr[2]), x3 = b2f((unsigned short)xr[3]);
    float dr = __expf(adt * (float)(63 - t));
    float xd0 = x0 * dr, xd1 = x1 * dr, xd2 = x2 * dr, xd3 = x3 * dr;
#pragma unroll
    for (int nn = 0; nn < 8; nn++) {
      float bv = Bs[t * 65 + ng + nn];
      acc1[nn][0] += bv * xd0; acc1[nn][1] += bv * xd1;
      acc1[nn][2] += bv * xd2; acc1[nn][3] += bv * xd3;
      float cv = Cb[(ng + nn) * 65 + t];
      acc2[nn][0] += cv * x0; acc2[nn][1] += cv * x1;
      acc2[nn][2] += cv * x2; acc2[nn][3] += cv * x3;
    }
  }
  size_t sb = ((size_t)((b * HS_ + h) * NC_ + c)) * (NS_ * PS_);
#pragma unroll
  for (int nn = 0; nn < 8; nn++) {
    *(float4*)&st[sb + (size_t)(ng + nn) * PS_ + pg * 4] =
        make_float4(acc1[nn][0] * dt, acc1[nn][1] * dt, acc1[nn][2] * dt, acc1[nn][3] * dt);
  }
#pragma unroll
  for (int qq = 0; qq < 8; qq++) {
    int qr = ng + qq;
    short4v xr = *(const short4v*)&Xh[qr * 128 + pg * 4];
    size_t yo = ((size_t)(b * L_ + l0 + qr)) * DI_ + h * PS_ + pg * 4;
    *(float4*)&y[yo] = make_float4(
        acc2[qq][0] * dt + Dp * b2f((unsigned short)xr[0]),
        acc2[qq][1] * dt + Dp * b2f((unsigned short)xr[1]),
        acc2[qq][2] * dt + Dp * b2f((unsigned short)xr[2]),
        acc2[qq][3] * dt + Dp * b2f((unsigned short)xr[3]));
  }
}

// ---------------- scan pass B1: inter-chunk recurrence, 128 blocks ----------------
__global__ __launch_bounds__(256) void scanB1_kernel(
    float* __restrict__ st, const float* __restrict__ dt_bias,
    const float* __restrict__ A_log) {
  int slice = blockIdx.x & 3;
  int h = (blockIdx.x >> 2) & 15, b = blockIdx.x >> 6;
  float dt = log1pf(__expf(dt_bias[h]));
  float adt = -__expf(A_log[h]) * dt;
  float cdec = __expf(adt * 64.f);
  size_t base = ((size_t)(b * HS_ + h)) * NC_ * (NS_ * PS_) + slice * 2048 + threadIdx.x;
  float hreg[8];
#pragma unroll
  for (int j = 0; j < 8; j++) hreg[j] = 0.f;
  for (int c = 0; c < NC_; c++) {
    size_t o = base + (size_t)c * (NS_ * PS_);
#pragma unroll
    for (int j = 0; j < 8; j++) {
      float tmp = st[o + (size_t)j * 256];
      st[o + (size_t)j * 256] = hreg[j];
      hreg[j] = cdec * hreg[j] + tmp;
    }
  }
}

// ---------------- scan pass B2: y_off + gate SiLU -> bf16; C at +1024 ----------------
__global__ __launch_bounds__(256) void scanB2_kernel(
    const __hip_bfloat16* __restrict__ BCm, const float* __restrict__ st,
    const __hip_bfloat16* __restrict__ vg, const float* __restrict__ dt_bias,
    const float* __restrict__ A_log, const float* __restrict__ y,
    __hip_bfloat16* __restrict__ yout) {
  __shared__ float Cs[64 * 64];
  __shared__ __align__(16) float Hs[64 * 128];
  int blk = blockIdx.x;
  int c = blk & 31, h = (blk >> 5) & 15, b = blk >> 9;
  float dt = log1pf(__expf(dt_bias[h]));
  float adt = -__expf(A_log[h]) * dt;
  int tid = threadIdx.x;
  int l0 = c * 64;
  size_t rC = ((size_t)(b * L_ + l0)) * 2048 + 1024 + h * NS_;
#pragma unroll
  for (int i = 0; i < 16; i++) {
    int e = tid + i * 256;
    int t = e >> 6, n = e & 63;
    Cs[t * 64 + n] = __bfloat162float(BCm[rC + (size_t)t * 2048 + n]);
  }
  size_t sb = ((size_t)((b * HS_ + h) * NC_ + c)) * (NS_ * PS_);
#pragma unroll
  for (int i = 0; i < 32; i++) {
    int e = tid + i * 256;
    Hs[e] = st[sb + e];
  }
  __syncthreads();
  int pg = tid & 31;
  int tg = (tid >> 5) << 3;
  float acc[8][4];
#pragma unroll
  for (int tt = 0; tt < 8; tt++)
#pragma unroll
    for (int i = 0; i < 4; i++) acc[tt][i] = 0.f;
  for (int n = 0; n < 64; n++) {
    float4 h4 = *(const float4*)&Hs[n * 128 + pg * 4];
#pragma unroll
    for (int tt = 0; tt < 8; tt++) {
      float cv = Cs[(tg + tt) * 64 + n];
      acc[tt][0] += cv * h4.x; acc[tt][1] += cv * h4.y;
      acc[tt][2] += cv * h4.z; acc[tt][3] += cv * h4.w;
    }
  }
#pragma unroll
  for (int tt = 0; tt < 8; tt++) {
    int t = tg + tt;
    float dout = __expf(adt * (float)(t + 1));
    size_t row = (size_t)(b * L_ + l0 + t);
#pragma unroll
    for (int i = 0; i < 4; i++) {
      int p = pg * 4 + i;
      float g = __bfloat162float(vg[row * 4096 + 2048 + h * PS_ + p]);
      float yv = y[row * DI_ + h * PS_ + p] + acc[tt][i] * dout;
      yout[row * DI_ + h * PS_ + p] = __float2bfloat16(yv * (g / (1.f + __expf(-g))));
    }
  }
}

// ---------------- rope tables ----------------
__global__ void rope_fill_kernel(float* __restrict__ cosb, float* __restrict__ sinb) {
  int idx = blockIdx.x * 256 + threadIdx.x;
  int i = idx & 31, l = idx >> 5;
  float inv = __expf(-(2.0f * (float)i / (float)PA_) * logf(10000.0f));
  float ang = (float)l * inv;
  cosb[idx] = cosf(ang);
  sinb[idx] = sinf(ang);
}

// ---------------- per-head rmsnorm + rope (+gain), bf16 strided src -> packed bf16 dst ----------------
__global__ __launch_bounds__(256) void qknorm_rope_bf16_kernel(
    const __hip_bfloat16* __restrict__ src, int srcstride, int srcofs,
    __hip_bfloat16* __restrict__ dst, int nh,
    const float* __restrict__ cosb, const float* __restrict__ sinb,
    const float* __restrict__ gain) {
  int row = blockIdx.x * 4 + (threadIdx.x >> 6);
  int lane = threadIdx.x & 63;
  int h = row % nh;
  int tok = row / nh;
  int l = tok & (L_ - 1);
  float v = __bfloat162float(src[(size_t)tok * srcstride + srcofs + h * 64 + lane]);
  float ss = v * v;
  for (int o = 32; o > 0; o >>= 1) ss += __shfl_xor(ss, o, 64);
  v *= rsqrtf(ss * (1.f / PA_) + RMS_EPS_);
  float partner = __shfl_xor(v, 32, 64);
  int i = lane & 31;
  float cth = cosb[l * 32 + i], sth = sinb[l * 32 + i];
  float out = (lane < 32) ? (v * cth + partner * sth) : (v * cth - partner * sth);
  if (gain) out *= gain[h];
  dst[(size_t)tok * (nh * 64) + h * 64 + lane] = __float2bfloat16(out);
}

// ---------------- causal GQA flash attention, bf16 MFMA ----------------
__global__ __launch_bounds__(256) void attn_mfma_kernel(
    const unsigned short* __restrict__ qb, const unsigned short* __restrict__ kb,
    const unsigned short* __restrict__ vt, const float* __restrict__ qgain,
    __hip_bfloat16* __restrict__ ao) {
  __shared__ unsigned short Ks[64][72];
  __shared__ unsigned short Vs[64][72];
  __shared__ unsigned short Psm[4][16][72];
  int blk = blockIdx.x;
  int qi = blk & 15;
  int h  = (blk >> 4) & 15;
  int b  = blk >> 8;
  int hk = h >> 2;
  int tid = threadIdx.x;
  int w = tid >> 6, l = tid & 63;
  int l15 = l & 15, lg = l >> 4;
  int r0 = tid >> 3, s0 = tid & 7;
  float mstat = 8.0f * fabsf(qgain[h]);
  const unsigned short* kbase = kb + (size_t)b * L_ * (HKV_ * PA_) + hk * PA_ + s0 * 8;
  const unsigned short* vbase = vt + ((size_t)(b * HKV_ + hk) * PA_) * L_ + s0 * 8;

  for (int pass = 0; pass < 2; pass++) {
    int qt = pass ? (31 - qi) : qi;
    int q0 = qt * 64;
    int qw = q0 + w * 16;
    short8 qf[2];
    {
      size_t qrow = ((size_t)(b * L_ + qw + l15)) * (HA_ * PA_) + h * PA_;
      qf[0] = *(const short8*)&qb[qrow + lg * 8];
      qf[1] = *(const short8*)&qb[qrow + 32 + lg * 8];
    }
    f32x4 o_acc[4];
#pragma unroll
    for (int db = 0; db < 4; db++) o_acc[db] = (f32x4){0.f, 0.f, 0.f, 0.f};
    f32x4 lsum = (f32x4){0.f, 0.f, 0.f, 0.f};
    int nkt = qt + 1;
    short8 kr0 = *(const short8*)&kbase[(size_t)r0 * (HKV_ * PA_)];
    short8 kr1 = *(const short8*)&kbase[(size_t)(r0 + 32) * (HKV_ * PA_)];
    short8 vr0 = *(const short8*)&vbase[(size_t)r0 * L_];
    short8 vr1 = *(const short8*)&vbase[(size_t)(r0 + 32) * L_];
    for (int kt = 0; kt < nkt; kt++) {
      int k0 = kt * 64;
      __syncthreads();
      *(short8*)&Ks[r0][s0 * 8] = kr0;
      *(short8*)&Ks[r0 + 32][s0 * 8] = kr1;
      *(short8*)&Vs[r0][s0 * 8] = vr0;
      *(short8*)&Vs[r0 + 32][s0 * 8] = vr1;
      if (kt + 1 < nkt) {
        int k1 = k0 + 64;
        kr0 = *(const short8*)&kbase[(size_t)(k1 + r0) * (HKV_ * PA_)];
        kr1 = *(const short8*)&kbase[(size_t)(k1 + r0 + 32) * (HKV_ * PA_)];
        vr0 = *(const short8*)&vbase[(size_t)r0 * L_ + k1];
        vr1 = *(const short8*)&vbase[(size_t)(r0 + 32) * L_ + k1];
      }
      __syncthreads();
      f32x4 s_acc[4];
#pragma unroll
      for (int kb2 = 0; kb2 < 4; kb2++) {
        short8 b0 = *(const short8*)&Ks[kb2 * 16 + l15][lg * 8];
        short8 b1 = *(const short8*)&Ks[kb2 * 16 + l15][32 + lg * 8];
        f32x4 s = (f32x4){0.f, 0.f, 0.f, 0.f};
        s = __builtin_amdgcn_mfma_f32_16x16x32_bf16(qf[0], b0, s, 0, 0, 0);
        s = __builtin_amdgcn_mfma_f32_16x16x32_bf16(qf[1], b1, s, 0, 0, 0);
        s_acc[kb2] = s;
      }
      bool diag = (kt == qt);
#pragma unroll
      for (int kb2 = 0; kb2 < 4; kb2++) {
        int key = k0 + kb2 * 16 + l15;
#pragma unroll
        for (int reg = 0; reg < 4; reg++) {
          float p = __expf(s_acc[kb2][reg] * 0.125f - mstat);
          if (diag && key > qw + lg * 4 + reg) p = 0.f;
          lsum[reg] += p;
          __hip_bfloat16 hv = __float2bfloat16(p);
          Psm[w][lg * 4 + reg][kb2 * 16 + l15] = *(unsigned short*)&hv;
        }
      }
      asm volatile("s_waitcnt lgkmcnt(0)" ::: "memory");
#pragma unroll
      for (int ks = 0; ks < 2; ks++) {
        short8 pa = *(const short8*)&Psm[w][l15][ks * 32 + lg * 8];
#pragma unroll
        for (int db = 0; db < 4; db++) {
          short8 vb8 = *(const short8*)&Vs[db * 16 + l15][ks * 32 + lg * 8];
          o_acc[db] = __builtin_amdgcn_mfma_f32_16x16x32_bf16(pa, vb8, o_acc[db], 0, 0, 0);
        }
      }
    }
#pragma unroll
    for (int of = 1; of < 16; of <<= 1) {
      lsum[0] += __shfl_xor(lsum[0], of, 64);
      lsum[1] += __shfl_xor(lsum[1], of, 64);
      lsum[2] += __shfl_xor(lsum[2], of, 64);
      lsum[3] += __shfl_xor(lsum[3], of, 64);
    }
#pragma unroll
    for (int reg = 0; reg < 4; reg++) {
      float invl = 1.0f / lsum[reg];
      size_t row = (size_t)(b * L_ + qw + lg * 4 + reg);
#pragma unroll
      for (int db = 0; db < 4; db++)
        ao[row * D_ + h * PA_ + db * 16 + l15] = __float2bfloat16(o_acc[db][reg] * invl);
    }
  }
}

// ---------------- host ----------------
extern "C" void kernel_launch(void* const* d_in, const int* in_sizes, int n_in,
                              void* d_out, int out_size, void* d_ws, size_t ws_size,
                              hipStream_t stream) {
  (void)in_sizes; (void)n_in; (void)out_size; (void)ws_size;
  const float* x           = (const float*)d_in[0];
  const float* in_proj_w   = (const float*)d_in[1];
  const float* conv_w      = (const float*)d_in[2];
  const float* conv_b      = (const float*)d_in[3];
  const float* B_proj_w    = (const float*)d_in[4];
  const float* C_proj_w    = (const float*)d_in[5];
  const float* dt_bias     = (const float*)d_in[6];
  const float* A_log       = (const float*)d_in[7];
  const float* D_param     = (const float*)d_in[8];
  const float* out_proj_w  = (const float*)d_in[9];
  const float* resid_mix_m = (const float*)d_in[10];
  const float* mamba_scale = (const float*)d_in[11];
  const float* m_fc_w      = (const float*)d_in[12];
  const float* m_proj_w    = (const float*)d_in[13];
  const float* m_mlp_scale = (const float*)d_in[14];
  const float* resid_mix_a = (const float*)d_in[15];
  const float* q_w         = (const float*)d_in[16];
  const float* k_w         = (const float*)d_in[17];
  const float* v_w         = (const float*)d_in[18];
  const float* o_w         = (const float*)d_in[19];
  const float* q_gain      = (const float*)d_in[20];
  const float* attn_scale  = (const float*)d_in[21];
  const float* a_fc_w      = (const float*)d_in[22];
  const float* a_proj_w    = (const float*)d_in[23];
  const float* a_mlp_scale = (const float*)d_in[24];
  float* ws  = (float*)d_ws;
  float* out = (float*)d_out;

  // ---- workspace layout (float units) ----
  float* xm    = ws;
  float* vgR   = ws + 4194304;
  float* xvR   = ws + 12582912;
  float* stR   = ws + 20971520;
  float* nbR   = ws + 29360128;
  float* xmbR  = ws + 31457280;
  float* BCR   = ws + 33554432;
  float* WtR   = ws + 37748736;
  float* cosb  = ws + 51642368;
  float* sinb  = cosb + 65536;

  __hip_bfloat16* vg   = (__hip_bfloat16*)vgR;      // [NT][4096] bf16 (value|gate)
  __hip_bfloat16* qkvb = (__hip_bfloat16*)vgR;      // [NT][1536] bf16 (attn phase)
  float*          yv   = xvR;                       // y f32 [NT][2048]
  float*          st   = stR;
  __hip_bfloat16* hb   = (__hip_bfloat16*)stR;
  __hip_bfloat16* nbb  = (__hip_bfloat16*)nbR;
  __hip_bfloat16* xmb  = (__hip_bfloat16*)xmbR;
  __hip_bfloat16* ybb  = (__hip_bfloat16*)nbR;
  __hip_bfloat16* BCm  = (__hip_bfloat16*)BCR;
  __hip_bfloat16* qbb  = (__hip_bfloat16*)xvR;                 // [NT][1024]
  __hip_bfloat16* kbb  = (__hip_bfloat16*)(xvR + 2097152);     // [NT][256]
  __hip_bfloat16* vtb  = (__hip_bfloat16*)(xvR + 2621440);     // [2][256][2048]
  __hip_bfloat16* aob  = (__hip_bfloat16*)(xvR + 3145728);     // [NT][1024]

  __hip_bfloat16* Wt = (__hip_bfloat16*)WtR;
  size_t o_in  = 0;
  size_t o_B   = o_in  + (size_t)4096 * 1024;
  size_t o_out = o_B   + (size_t)2048 * 1024;
  size_t o_mfc = o_out + (size_t)1024 * 2048;
  size_t o_mpj = o_mfc + (size_t)4096 * 1024;
  size_t o_qkv = o_mpj + (size_t)1024 * 4096;
  size_t o_o   = o_qkv + (size_t)1536 * 1024;
  size_t o_afc = o_o   + (size_t)1024 * 1024;
  size_t o_apj = o_afc + (size_t)4096 * 1024;

#define TCVT(Wp, off, K, N) \
  transpose_cvt<<<dim3((N) / 32, (K) / 32), 256, 0, stream>>>((Wp), Wt + (off), (K), (N), (N))
  TCVT(in_proj_w,  o_in,  1024, 4096);
  TCVT(B_proj_w,   o_B,   1024, 1024);
  TCVT(C_proj_w,   o_B + (size_t)1024 * 1024, 1024, 1024);
  TCVT(out_proj_w, o_out, 2048, 1024);
  TCVT(m_fc_w,     o_mfc, 1024, 4096);
  TCVT(m_proj_w,   o_mpj, 4096, 1024);
  TCVT(q_w,        o_qkv, 1024, 1024);
  TCVT(k_w,        o_qkv + (size_t)1024 * 1024, 1024, 256);
  TCVT(v_w,        o_qkv + (size_t)1280 * 1024, 1024, 256);
  TCVT(o_w,        o_o,   1024, 1024);
  TCVT(a_fc_w,     o_afc, 1024, 4096);
  TCVT(a_proj_w,   o_apj, 4096, 1024);
#undef TCVT

#define GEMM(BN, Abuf, Woff, Cfp, Cbp, basep, scalep, N, K, mode, rsh) \
  gemm_bf16_t<BN><<<32 * ((N) / (BN)), 256, 0, stream>>>( \
      (const unsigned short*)(Abuf), (const unsigned short*)(Wt + (Woff)), \
      (Cfp), (Cbp), (basep), (scalep), (N), (K), (N) / (BN), (mode), (rsh))
#define GEMM64(Abuf, Woff, Cfp, Cbop, basep, scalep, N, K, mode) \
  gemm64<<<64 * ((N) / 64), 256, 0, stream>>>( \
      (const unsigned short*)(Abuf), (const unsigned short*)(Wt + (Woff)), \
      (Cfp), (Cbop), (basep), (scalep), (N), (K), (mode))
#define GEMM256(MODE, Abuf, Woff, Cbp) \
  gemm256_k32<MODE><<<256, 512, 0, stream>>>( \
      (const unsigned short*)(Abuf), (const unsigned short*)(Wt + (Woff)), \
      (Cbp), 4096, 1024)

  // --- mamba branch ---
  mix_rms_kernel<<<NT_, 256, 0, stream>>>(x, x, resid_mix_m, xm, nbb, xmb);
  GEMM256(2, nbb, o_in, vg);
  GEMM(128, xmb, o_B, (float*)0, BCm, (const float*)0, (const float*)0, 2048, 1024, 2, 0);
  scanAF_kernel<<<B_ * HS_ * NC_, 256, 0, stream>>>(vg, BCm, conv_w, conv_b,
                                                    dt_bias, A_log, D_param, st, yv);
  scanB1_kernel<<<B_ * HS_ * 4, 256, 0, stream>>>(st, dt_bias, A_log);
  scanB2_kernel<<<B_ * HS_ * NC_, 256, 0, stream>>>(BCm, st, vg, dt_bias, A_log, yv, ybb);
  GEMM64(ybb, o_out, xm, (__hip_bfloat16*)0, xm, mamba_scale, 1024, 2048, 3);
  // --- mamba MLP ---
  rms_kernel<<<NT_, 256, 0, stream>>>(xm, nbb);
  GEMM256(1, nbb, o_mfc, hb);
  GEMM64(hb, o_mpj, xm, (__hip_bfloat16*)0, xm, m_mlp_scale, 1024, 4096, 3);
  // --- attention branch ---
  mix_rms_kernel<<<NT_, 256, 0, stream>>>(xm, x, resid_mix_a, xm, nbb, (__hip_bfloat16*)0);
  GEMM64(nbb, o_qkv, (float*)0, qkvb, (const float*)0, (const float*)0, 1536, 1024, 2);
  rope_fill_kernel<<<L_ * 32 / 256, 256, 0, stream>>>(cosb, sinb);
  qknorm_rope_bf16_kernel<<<NT_ * HA_ / 4, 256, 0, stream>>>(qkvb, 1536, 0, qbb, HA_, cosb, sinb, q_gain);
  qknorm_rope_bf16_kernel<<<NT_ * HKV_ / 4, 256, 0, stream>>>(qkvb, 1536, 1024, kbb, HKV_, cosb, sinb, (const float*)0);
  transpose_bf16<<<dim3(256 / 32, 2048 / 32), 256, 0, stream>>>(
      (const unsigned short*)qkvb + 1280, (unsigned short*)vtb, 2048, 256, 1536);
  transpose_bf16<<<dim3(256 / 32, 2048 / 32), 256, 0, stream>>>(
      (const unsigned short*)qkvb + (size_t)L_ * 1536 + 1280,
      (unsigned short*)vtb + (size_t)256 * L_, 2048, 256, 1536);
  attn_mfma_kernel<<<B_ * HA_ * 16, 256, 0, stream>>>(
      (const unsigned short*)qbb, (const unsigned short*)kbb, (const unsigned short*)vtb,
      q_gain, aob);
  GEMM64(aob, o_o, xm, (__hip_bfloat16*)0, xm, attn_scale, 1024, 1024, 3);
  // --- attention MLP ---
  rms_kernel<<<NT_, 256, 0, stream>>>(xm, nbb);
  GEMM256(1, nbb, o_afc, hb);
  GEMM64(hb, o_apj, out, (__hip_bfloat16*)0, xm, a_mlp_scale, 1024, 4096, 3);
#undef GEMM
#undef GEMM64
#undef GEMM256
}

// Round 17
// 619.592 us; speedup vs baseline: 1.0537x; 1.0259x over previous
//
#include <hip/hip_runtime.h>
#include <hip/hip_bf16.h>
#include <math.h>

#define D_ 1024
#define DI_ 2048
#define HS_ 16
#define PS_ 128
#define NS_ 64
#define HA_ 16
#define HKV_ 4
#define PA_ 64
#define B_ 2
#define L_ 2048
#define NT_ 4096          // B_*L_
#define NC_ 32            // L_/64
#define RMS_EPS_ 1.1920929e-7f

typedef __attribute__((ext_vector_type(8))) short short8;
typedef __attribute__((ext_vector_type(4))) short short4v;
typedef __attribute__((ext_vector_type(4))) float f32x4;

#define GLOAD_LDS16(gp, lp)                                                        \
  __builtin_amdgcn_global_load_lds(                                               \
      (const __attribute__((address_space(1))) unsigned int*)(gp),                \
      (__attribute__((address_space(3))) unsigned int*)(lp), 16, 0, 0)

__device__ __forceinline__ float b2f(unsigned short u) {
  union { unsigned int i; float f; } x;
  x.i = ((unsigned int)u) << 16;
  return x.f;
}

// ---------------- transpose + fp32->bf16: W[K rows x N cols, row-stride ldw] -> Wt[N][K] ----------------
__global__ __launch_bounds__(256) void transpose_cvt(
    const float* __restrict__ W, __hip_bfloat16* __restrict__ Wt, int K, int N, int ldw) {
  __shared__ float t[32][33];
  int n0 = blockIdx.x * 32, k0 = blockIdx.y * 32;
  int tx = threadIdx.x & 31, ty = threadIdx.x >> 5;
#pragma unroll
  for (int i = 0; i < 4; i++)
    t[ty + i * 8][tx] = W[(size_t)(k0 + ty + i * 8) * ldw + n0 + tx];
  __syncthreads();
#pragma unroll
  for (int i = 0; i < 4; i++)
    Wt[(size_t)(n0 + ty + i * 8) * K + k0 + tx] = __float2bfloat16(t[tx][ty + i * 8]);
}

// ---------------- transpose bf16 -> bf16 ----------------
__global__ __launch_bounds__(256) void transpose_bf16(
    const unsigned short* __restrict__ S, unsigned short* __restrict__ D,
    int K, int N, int lds) {
  __shared__ unsigned short t[32][33];
  int n0 = blockIdx.x * 32, k0 = blockIdx.y * 32;
  int tx = threadIdx.x & 31, ty = threadIdx.x >> 5;
#pragma unroll
  for (int i = 0; i < 4; i++)
    t[ty + i * 8][tx] = S[(size_t)(k0 + ty + i * 8) * lds + n0 + tx];
  __syncthreads();
#pragma unroll
  for (int i = 0; i < 4; i++)
    D[(size_t)(n0 + ty + i * 8) * K + k0 + tx] = t[tx][ty + i * 8];
}

// ---------------- 256x256 tile, BK=32, 3-stage pipelined bf16 GEMM (N=4096,K=1024) ----------------
template<int MODE>
__global__ __launch_bounds__(512) void gemm256_k32(
    const unsigned short* __restrict__ A, const unsigned short* __restrict__ Wt,
    __hip_bfloat16* __restrict__ Cb, int N, int K) {
  __shared__ unsigned short As[3][256 * 32];
  __shared__ unsigned short Bs[3][256 * 32];
  int lid = blockIdx.x;
  int x = lid & 7, r = lid >> 3;
  int bm = ((x >> 2) * 8 + (r & 7)) * 256;
  int bn = ((x & 3) * 4 + (r >> 3)) * 256;
  int tid = threadIdx.x;
  int w = tid >> 6, l = tid & 63;
  int wr = w >> 2, wc = w & 3;
  int l15 = l & 15, lg = l >> 4;
  int rr = tid >> 2, ss = tid & 3;

  f32x4 acc[8][4];
#pragma unroll
  for (int i = 0; i < 8; i++)
#pragma unroll
    for (int j = 0; j < 4; j++) acc[i][j] = (f32x4){0.f, 0.f, 0.f, 0.f};

  auto STAGE = [&](int kt, int nb) {
    int k0 = kt * 32;
#pragma unroll
    for (int p = 0; p < 2; p++) {
      int row = p * 128 + rr;
      int kq = ss ^ ((row >> 1) & 3);
      GLOAD_LDS16(A + (size_t)(bm + row) * K + k0 + kq * 8, &As[nb][row * 32 + ss * 8]);
    }
#pragma unroll
    for (int p = 0; p < 2; p++) {
      int row = p * 128 + rr;
      int kq = ss ^ ((row >> 1) & 3);
      GLOAD_LDS16(Wt + (size_t)(bn + row) * K + k0 + kq * 8, &Bs[nb][row * 32 + ss * 8]);
    }
  };

  int KT = K >> 5;
  STAGE(0, 0);
  STAGE(1, 1);
  int buf = 0;
  for (int t = 0; t < KT; ++t) {
    if (t + 1 < KT) {
      asm volatile("s_waitcnt vmcnt(4)" ::: "memory");
    } else {
      asm volatile("s_waitcnt vmcnt(0)" ::: "memory");
    }
    __builtin_amdgcn_s_barrier();
    __builtin_amdgcn_sched_barrier(0);
    if (t + 2 < KT) STAGE(t + 2, (t + 2) % 3);
    short8 bf[4];
#pragma unroll
    for (int j = 0; j < 4; j++) {
      int row = wc * 64 + j * 16 + l15;
      bf[j] = *(const short8*)&Bs[buf][row * 32 + ((lg ^ ((row >> 1) & 3)) << 3)];
    }
#pragma unroll
    for (int i = 0; i < 8; i++) {
      int row = wr * 128 + i * 16 + l15;
      short8 af = *(const short8*)&As[buf][row * 32 + ((lg ^ ((row >> 1) & 3)) << 3)];
#pragma unroll
      for (int j = 0; j < 4; j++)
        acc[i][j] = __builtin_amdgcn_mfma_f32_16x16x32_bf16(af, bf[j], acc[i][j], 0, 0, 0);
    }
    buf = (buf == 2) ? 0 : buf + 1;
  }
#pragma unroll
  for (int i = 0; i < 8; i++)
#pragma unroll
    for (int j = 0; j < 4; j++) {
      int gr = bm + wr * 128 + i * 16 + lg * 4;
      int gc = bn + wc * 64 + j * 16 + l15;
#pragma unroll
      for (int reg = 0; reg < 4; reg++) {
        float v = acc[i][j][reg];
        if (MODE == 1) { v = fmaxf(v, 0.f); v = v * v; }
        Cb[(size_t)(gr + reg) * N + gc] = __float2bfloat16(v);
      }
    }
}

// ---------------- bf16 MFMA GEMM, BK=64 double-buffered, tile 128 x BN (BC proj) ----------------
template<int BN>
__global__ __launch_bounds__(256) void gemm_bf16_t(
    const unsigned short* __restrict__ A, const unsigned short* __restrict__ Wt,
    float* __restrict__ Cf, __hip_bfloat16* __restrict__ Cb,
    const float* __restrict__ baseb, const float* __restrict__ scale,
    int N, int K, int gn, int mode, int rsh) {
  constexpr int nWc = BN / 64;
  constexpr int nWr = 4 / nWc;
  constexpr int MF  = 8 / nWr;
  __shared__ unsigned short As[2][128 * 64];
  __shared__ unsigned short Bs[2][BN * 64];
  int lid = blockIdx.x;
  int x = lid & 7, r = lid >> 3;
  int bm, bn;
  if (rsh == 0) {
    int RN = gn >> 2;
    bm = ((x >> 2) * 16 + (r & 15)) * 128;
    bn = ((x & 3) * RN + (r >> 4)) * BN;
  } else {
    bm = (x * 4 + (r & 3)) * 128;
    bn = (r >> 2) * BN;
  }
  int tid = threadIdx.x;
  int w = tid >> 6, l = tid & 63;
  int wr = w / nWc, wc = w % nWc;
  int l15 = l & 15, lg = l >> 4;
  f32x4 acc[MF][4];
#pragma unroll
  for (int i = 0; i < MF; i++)
#pragma unroll
    for (int j = 0; j < 4; j++) acc[i][j] = (f32x4){0.f, 0.f, 0.f, 0.f};
  int r_ = tid >> 3;
  int s_ = tid & 7;

  auto STAGE = [&](int k0, int nb) {
#pragma unroll
    for (int i = 0; i < 4; i++) {
      int rr = i * 32 + r_;
      int kq = s_ ^ (rr & 7);
      GLOAD_LDS16(A + (size_t)(bm + rr) * K + k0 + kq * 8, &As[nb][rr * 64 + s_ * 8]);
    }
#pragma unroll
    for (int i = 0; i < BN / 32; i++) {
      int rr = i * 32 + r_;
      int kq = s_ ^ (rr & 7);
      GLOAD_LDS16(Wt + (size_t)(bn + rr) * K + k0 + kq * 8, &Bs[nb][rr * 64 + s_ * 8]);
    }
  };

  STAGE(0, 0);
  __syncthreads();
  int cur = 0;
  for (int k0 = 0; k0 < K; k0 += 64) {
    if (k0 + 64 < K) STAGE(k0 + 64, cur ^ 1);
#pragma unroll
    for (int h = 0; h < 2; h++) {
      short8 af[MF], bfr[4];
#pragma unroll
      for (int i = 0; i < MF; i++) {
        int row = wr * (16 * MF) + i * 16 + l15;
        int c = h * 4 + lg;
        af[i] = *(const short8*)&As[cur][row * 64 + ((c ^ (row & 7)) << 3)];
      }
#pragma unroll
      for (int j = 0; j < 4; j++) {
        int row = wc * 64 + j * 16 + l15;
        int c = h * 4 + lg;
        bfr[j] = *(const short8*)&Bs[cur][row * 64 + ((c ^ (row & 7)) << 3)];
      }
#pragma unroll
      for (int i = 0; i < MF; i++)
#pragma unroll
        for (int j = 0; j < 4; j++)
          acc[i][j] = __builtin_amdgcn_mfma_f32_16x16x32_bf16(af[i], bfr[j], acc[i][j], 0, 0, 0);
    }
    __syncthreads();
    cur ^= 1;
  }
  int rb = lg * 4, cb2 = l15;
#pragma unroll
  for (int i = 0; i < MF; i++)
#pragma unroll
    for (int j = 0; j < 4; j++) {
      int gr = bm + wr * (16 * MF) + i * 16 + rb;
      int gc = bn + wc * 64 + j * 16 + cb2;
#pragma unroll
      for (int reg = 0; reg < 4; reg++) {
        float v = acc[i][j][reg];
        size_t idx = (size_t)(gr + reg) * N + gc;
        if (mode == 0) {
          Cf[idx] = v;
        } else if (mode == 1) {
          v = fmaxf(v, 0.f);
          Cb[idx] = __float2bfloat16(v * v);
        } else if (mode == 2) {
          Cb[idx] = __float2bfloat16(v);
        } else {
          Cf[idx] = baseb[idx] + scale[gc] * v;
        }
      }
    }
}

// ---------------- 64x64 tile bf16 GEMM, BK=64, 2-buffer ----------------
// mode 0: f32 out; 2: bf16 out; 3: f32 = base + scale[col]*acc. Grid = 64*(N/64); M=4096.
__global__ __launch_bounds__(256) void gemm64(
    const unsigned short* __restrict__ A, const unsigned short* __restrict__ Wt,
    float* __restrict__ Cf, __hip_bfloat16* __restrict__ Cbo,
    const float* __restrict__ baseb, const float* __restrict__ scale,
    int N, int K, int mode) {
  __shared__ unsigned short As[2][64 * 64];
  __shared__ unsigned short Bs[2][64 * 64];
  int lid = blockIdx.x;
  int x = lid & 7, r = lid >> 3;
  int bm = (x * 8 + (r & 7)) * 64;
  int bn = (r >> 3) * 64;
  int tid = threadIdx.x;
  int w = tid >> 6, l = tid & 63;
  int l15 = l & 15, lg = l >> 4;
  f32x4 acc[4];
#pragma unroll
  for (int j = 0; j < 4; j++) acc[j] = (f32x4){0.f, 0.f, 0.f, 0.f};
  int r_ = tid >> 3;
  int s_ = tid & 7;

  auto STAGE = [&](int k0, int nb) {
#pragma unroll
    for (int i = 0; i < 2; i++) {
      int row = i * 32 + r_;
      int kq = s_ ^ (row & 7);
      GLOAD_LDS16(A + (size_t)(bm + row) * K + k0 + kq * 8, &As[nb][row * 64 + s_ * 8]);
    }
#pragma unroll
    for (int i = 0; i < 2; i++) {
      int row = i * 32 + r_;
      int kq = s_ ^ (row & 7);
      GLOAD_LDS16(Wt + (size_t)(bn + row) * K + k0 + kq * 8, &Bs[nb][row * 64 + s_ * 8]);
    }
  };

  STAGE(0, 0);
  __syncthreads();
  int cur = 0;
  for (int k0 = 0; k0 < K; k0 += 64) {
    if (k0 + 64 < K) STAGE(k0 + 64, cur ^ 1);
#pragma unroll
    for (int h = 0; h < 2; h++) {
      int c = h * 4 + lg;
      int arow = w * 16 + l15;
      short8 af = *(const short8*)&As[cur][arow * 64 + ((c ^ (arow & 7)) << 3)];
#pragma unroll
      for (int j = 0; j < 4; j++) {
        int brow = j * 16 + l15;
        short8 bfr = *(const short8*)&Bs[cur][brow * 64 + ((c ^ (brow & 7)) << 3)];
        acc[j] = __builtin_amdgcn_mfma_f32_16x16x32_bf16(af, bfr, acc[j], 0, 0, 0);
      }
    }
    __syncthreads();
    cur ^= 1;
  }
#pragma unroll
  for (int j = 0; j < 4; j++) {
    int gr = bm + w * 16 + lg * 4;
    int gc = bn + j * 16 + l15;
#pragma unroll
    for (int reg = 0; reg < 4; reg++) {
      float v = acc[j][reg];
      size_t idx = (size_t)(gr + reg) * N + gc;
      if (mode == 0)      Cf[idx] = v;
      else if (mode == 2) Cbo[idx] = __float2bfloat16(v);
      else                Cf[idx] = baseb[idx] + scale[gc] * v;
    }
  }
}

// ---------------- mix + rmsnorm ----------------
__global__ __launch_bounds__(256) void mix_rms_kernel(
    const float* __restrict__ a, const float* __restrict__ b2,
    const float* __restrict__ mix, float* __restrict__ xout,
    __hip_bfloat16* __restrict__ nbf, __hip_bfloat16* __restrict__ rawbf) {
  int row = blockIdx.x;
  size_t base = (size_t)row * D_;
  float v[4]; float ss = 0.f;
#pragma unroll
  for (int i = 0; i < 4; i++) {
    int d = threadIdx.x + i * 256;
    float val = mix[d] * a[base + d] + mix[D_ + d] * b2[base + d];
    v[i] = val; ss += val * val;
  }
  for (int o = 32; o > 0; o >>= 1) ss += __shfl_down(ss, o, 64);
  __shared__ float red[4];
  if ((threadIdx.x & 63) == 0) red[threadIdx.x >> 6] = ss;
  __syncthreads();
  float inv = rsqrtf((red[0] + red[1] + red[2] + red[3]) * (1.f / D_) + RMS_EPS_);
#pragma unroll
  for (int i = 0; i < 4; i++) {
    int d = threadIdx.x + i * 256;
    xout[base + d] = v[i];
    nbf[base + d] = __float2bfloat16(v[i] * inv);
    if (rawbf) rawbf[base + d] = __float2bfloat16(v[i]);
  }
}

__global__ __launch_bounds__(256) void rms_kernel(
    const float* __restrict__ a, __hip_bfloat16* __restrict__ nbf) {
  int row = blockIdx.x;
  size_t base = (size_t)row * D_;
  float v[4]; float ss = 0.f;
#pragma unroll
  for (int i = 0; i < 4; i++) {
    int d = threadIdx.x + i * 256;
    float val = a[base + d];
    v[i] = val; ss += val * val;
  }
  for (int o = 32; o > 0; o >>= 1) ss += __shfl_down(ss, o, 64);
  __shared__ float red[4];
  if ((threadIdx.x & 63) == 0) red[threadIdx.x >> 6] = ss;
  __syncthreads();
  float inv = rsqrtf((red[0] + red[1] + red[2] + red[3]) * (1.f / D_) + RMS_EPS_);
#pragma unroll
  for (int i = 0; i < 4; i++) {
    int d = threadIdx.x + i * 256;
    nbf[base + d] = __float2bfloat16(v[i] * inv);
  }
}

// ---------------- FUSED conv+SiLU + scanA1(states) + scanA2(y_diag) ----------------
// Vectorized LDS: Bs f32 [64][68], Cq/Cbt f32 [64][68], Xh bf16 [64][128].
// Merged loop: 5 LDS reads/t (2x f32x4 Bs + 2x f32x4 Cbt + 1x b64 Xh).
__global__ __launch_bounds__(256) void scanAF_kernel(
    const __hip_bfloat16* __restrict__ vg, const __hip_bfloat16* __restrict__ BCm,
    const float* __restrict__ cw, const float* __restrict__ cbias,
    const float* __restrict__ dt_bias, const float* __restrict__ A_log,
    const float* __restrict__ D_param, float* __restrict__ st, float* __restrict__ y) {
  __shared__ __align__(16) float sm[12800];           // 51200 B
  unsigned short* Xh = (unsigned short*)sm;           // [64][128] bf16 (16384 B)
  float* Bs = sm + 4096;                              // [64][68] f32 (17408 B); Vg overlays
  unsigned short* Vg = (unsigned short*)(sm + 4096);  // [67][128] bf16 (17152 B)
  float* Cq = sm + 8448;                              // [64][68] f32: C rows, then CBL^T
  int blk = blockIdx.x;
  int c = blk & 31, h = (blk >> 5) & 15, b = blk >> 9;
  float dt = log1pf(__expf(dt_bias[h]));
  float adt = -__expf(A_log[h]) * dt;
  float Dp = D_param[h];
  int tid = threadIdx.x;
  int l0 = c * 64;
  size_t rBC = ((size_t)(b * L_ + l0)) * 2048 + h * NS_;
  // stage C (short8 -> f32 [64][68]) and Vg halo
#pragma unroll
  for (int i = 0; i < 2; i++) {
    int e = tid + i * 256;                 // 512 chunks of 8
    int t = e >> 3, s = e & 7;
    short8 v = *(const short8*)((const unsigned short*)BCm + rBC + 1024 + (size_t)t * 2048 + s * 8);
    f32x4 lo = (f32x4){b2f((unsigned short)v[0]), b2f((unsigned short)v[1]),
                       b2f((unsigned short)v[2]), b2f((unsigned short)v[3])};
    f32x4 hi = (f32x4){b2f((unsigned short)v[4]), b2f((unsigned short)v[5]),
                       b2f((unsigned short)v[6]), b2f((unsigned short)v[7])};
    *(f32x4*)&Cq[t * 68 + s * 8] = lo;
    *(f32x4*)&Cq[t * 68 + s * 8 + 4] = hi;
  }
  for (int k = 0; k < 5; k++) {
    int e = tid + k * 256;
    if (e < 1072) {
      int rr = e >> 4, s = e & 15;
      int gl = l0 - 3 + rr;
      short8 v;
      if (gl < 0) v = (short8){0, 0, 0, 0, 0, 0, 0, 0};
      else v = *(const short8*)((const unsigned short*)vg +
                ((size_t)(b * L_ + gl)) * 4096 + h * PS_ + s * 8);
      *(short8*)&Vg[rr * 128 + s * 8] = v;
    }
  }
  __syncthreads();
  // conv (4 taps) + SiLU -> Xh bf16
  {
    int p4 = (tid & 31) * 4;
    int t0 = (tid >> 5) * 8;
    float w0[4], w1[4], w2[4], w3[4], bb[4];
#pragma unroll
    for (int q = 0; q < 4; q++) {
      int ch = h * PS_ + p4 + q;
      w0[q] = cw[ch * 4 + 0]; w1[q] = cw[ch * 4 + 1];
      w2[q] = cw[ch * 4 + 2]; w3[q] = cw[ch * 4 + 3];
      bb[q] = cbias[ch];
    }
#pragma unroll
    for (int i = 0; i < 8; i++) {
      int t = t0 + i;
      short4v r0 = *(const short4v*)&Vg[(t + 0) * 128 + p4];
      short4v r1 = *(const short4v*)&Vg[(t + 1) * 128 + p4];
      short4v r2 = *(const short4v*)&Vg[(t + 2) * 128 + p4];
      short4v r3 = *(const short4v*)&Vg[(t + 3) * 128 + p4];
      short4v o;
#pragma unroll
      for (int q = 0; q < 4; q++) {
        float a = bb[q] + w0[q] * b2f((unsigned short)r0[q])
                        + w1[q] * b2f((unsigned short)r1[q])
                        + w2[q] * b2f((unsigned short)r2[q])
                        + w3[q] * b2f((unsigned short)r3[q]);
        float sv = a / (1.f + __expf(-a));
        __hip_bfloat16 hv = __float2bfloat16(sv);
        o[q] = *(short*)&hv;
      }
      *(short4v*)&Xh[t * 128 + p4] = o;
    }
  }
  __syncthreads();                 // Vg reads done; Xh ready
  // stage B (short8 -> f32 [64][68]) over Vg region
#pragma unroll
  for (int i = 0; i < 2; i++) {
    int e = tid + i * 256;
    int t = e >> 3, s = e & 7;
    short8 v = *(const short8*)((const unsigned short*)BCm + rBC + (size_t)t * 2048 + s * 8);
    f32x4 lo = (f32x4){b2f((unsigned short)v[0]), b2f((unsigned short)v[1]),
                       b2f((unsigned short)v[2]), b2f((unsigned short)v[3])};
    f32x4 hi = (f32x4){b2f((unsigned short)v[4]), b2f((unsigned short)v[5]),
                       b2f((unsigned short)v[6]), b2f((unsigned short)v[7])};
    *(f32x4*)&Bs[t * 68 + s * 8] = lo;
    *(f32x4*)&Bs[t * 68 + s * 8 + 4] = hi;
  }
  __syncthreads();
  // CBL: hoist C row -> regs; vectorized dot; causal mask; write transposed
  int q_ = tid >> 2;
  int kb = (tid & 3) << 4;
  f32x4 creg[16];
#pragma unroll
  for (int n4 = 0; n4 < 16; n4++) creg[n4] = *(const f32x4*)&Cq[q_ * 68 + n4 * 4];
  float cbl[16];
#pragma unroll
  for (int kk = 0; kk < 16; kk++) {
    int k = kb + kk;
    f32x4 s4 = (f32x4){0.f, 0.f, 0.f, 0.f};
#pragma unroll
    for (int n4 = 0; n4 < 16; n4++)
      s4 += creg[n4] * (*(const f32x4*)&Bs[k * 68 + n4 * 4]);
    float a = s4[0] + s4[1] + s4[2] + s4[3];
    a = (k <= q_) ? a * __expf(adt * (float)(q_ - k)) : 0.f;
    cbl[kk] = a;
  }
  __syncthreads();                 // all C-row reads complete
#pragma unroll
  for (int kk = 0; kk < 16; kk++) Cq[(kb + kk) * 68 + q_] = cbl[kk];   // Cbt[t][q]
  __syncthreads();
  // merged A1 (states) + A2 (y_diag) pass over Xh — 5 LDS reads/t
  int pg = tid & 31;
  int ng = (tid >> 5) << 3;
  float acc1[8][4], acc2[8][4];
#pragma unroll
  for (int nn = 0; nn < 8; nn++)
#pragma unroll
    for (int i = 0; i < 4; i++) { acc1[nn][i] = 0.f; acc2[nn][i] = 0.f; }
  for (int t = 0; t < 64; t++) {
    f32x4 b0 = *(const f32x4*)&Bs[t * 68 + ng];
    f32x4 b1 = *(const f32x4*)&Bs[t * 68 + ng + 4];
    f32x4 c0 = *(const f32x4*)&Cq[t * 68 + ng];
    f32x4 c1 = *(const f32x4*)&Cq[t * 68 + ng + 4];
    short4v xr = *(const short4v*)&Xh[t * 128 + pg * 4];
    float x0 = b2f((unsigned short)xr[0]), x1 = b2f((unsigned short)xr[1]);
    float x2 = b2f((unsigned short)xr[2]), x3 = b2f((unsigned short)xr[3]);
    float dr = __expf(adt * (float)(63 - t));
    float xd0 = x0 * dr, xd1 = x1 * dr, xd2 = x2 * dr, xd3 = x3 * dr;
#pragma unroll
    for (int nn = 0; nn < 4; nn++) {
      float bv = b0[nn], cv = c0[nn];
      acc1[nn][0] += bv * xd0; acc1[nn][1] += bv * xd1;
      acc1[nn][2] += bv * xd2; acc1[nn][3] += bv * xd3;
      acc2[nn][0] += cv * x0; acc2[nn][1] += cv * x1;
      acc2[nn][2] += cv * x2; acc2[nn][3] += cv * x3;
    }
#pragma unroll
    for (int nn = 0; nn < 4; nn++) {
      float bv = b1[nn], cv = c1[nn];
      acc1[nn + 4][0] += bv * xd0; acc1[nn + 4][1] += bv * xd1;
      acc1[nn + 4][2] += bv * xd2; acc1[nn + 4][3] += bv * xd3;
      acc2[nn + 4][0] += cv * x0; acc2[nn + 4][1] += cv * x1;
      acc2[nn + 4][2] += cv * x2; acc2[nn + 4][3] += cv * x3;
    }
  }
  size_t sb = ((size_t)((b * HS_ + h) * NC_ + c)) * (NS_ * PS_);
#pragma unroll
  for (int nn = 0; nn < 8; nn++) {
    *(float4*)&st[sb + (size_t)(ng + nn) * PS_ + pg * 4] =
        make_float4(acc1[nn][0] * dt, acc1[nn][1] * dt, acc1[nn][2] * dt, acc1[nn][3] * dt);
  }
#pragma unroll
  for (int qq = 0; qq < 8; qq++) {
    int qr = ng + qq;
    short4v xr = *(const short4v*)&Xh[qr * 128 + pg * 4];
    size_t yo = ((size_t)(b * L_ + l0 + qr)) * DI_ + h * PS_ + pg * 4;
    *(float4*)&y[yo] = make_float4(
        acc2[qq][0] * dt + Dp * b2f((unsigned short)xr[0]),
        acc2[qq][1] * dt + Dp * b2f((unsigned short)xr[1]),
        acc2[qq][2] * dt + Dp * b2f((unsigned short)xr[2]),
        acc2[qq][3] * dt + Dp * b2f((unsigned short)xr[3]));
  }
}

// ---------------- scan pass B1: inter-chunk recurrence, 128 blocks ----------------
__global__ __launch_bounds__(256) void scanB1_kernel(
    float* __restrict__ st, const float* __restrict__ dt_bias,
    const float* __restrict__ A_log) {
  int slice = blockIdx.x & 3;
  int h = (blockIdx.x >> 2) & 15, b = blockIdx.x >> 6;
  float dt = log1pf(__expf(dt_bias[h]));
  float adt = -__expf(A_log[h]) * dt;
  float cdec = __expf(adt * 64.f);
  size_t base = ((size_t)(b * HS_ + h)) * NC_ * (NS_ * PS_) + slice * 2048 + threadIdx.x;
  float hreg[8];
#pragma unroll
  for (int j = 0; j < 8; j++) hreg[j] = 0.f;
  for (int c = 0; c < NC_; c++) {
    size_t o = base + (size_t)c * (NS_ * PS_);
#pragma unroll
    for (int j = 0; j < 8; j++) {
      float tmp = st[o + (size_t)j * 256];
      st[o + (size_t)j * 256] = hreg[j];
      hreg[j] = cdec * hreg[j] + tmp;
    }
  }
}

// ---------------- scan pass B2: y_off + gate SiLU -> bf16; C at +1024 ----------------
__global__ __launch_bounds__(256) void scanB2_kernel(
    const __hip_bfloat16* __restrict__ BCm, const float* __restrict__ st,
    const __hip_bfloat16* __restrict__ vg, const float* __restrict__ dt_bias,
    const float* __restrict__ A_log, const float* __restrict__ y,
    __hip_bfloat16* __restrict__ yout) {
  __shared__ float Cs[64 * 64];
  __shared__ __align__(16) float Hs[64 * 128];
  int blk = blockIdx.x;
  int c = blk & 31, h = (blk >> 5) & 15, b = blk >> 9;
  float dt = log1pf(__expf(dt_bias[h]));
  float adt = -__expf(A_log[h]) * dt;
  int tid = threadIdx.x;
  int l0 = c * 64;
  size_t rC = ((size_t)(b * L_ + l0)) * 2048 + 1024 + h * NS_;
#pragma unroll
  for (int i = 0; i < 16; i++) {
    int e = tid + i * 256;
    int t = e >> 6, n = e & 63;
    Cs[t * 64 + n] = __bfloat162float(BCm[rC + (size_t)t * 2048 + n]);
  }
  size_t sb = ((size_t)((b * HS_ + h) * NC_ + c)) * (NS_ * PS_);
#pragma unroll
  for (int i = 0; i < 32; i++) {
    int e = tid + i * 256;
    Hs[e] = st[sb + e];
  }
  __syncthreads();
  int pg = tid & 31;
  int tg = (tid >> 5) << 3;
  float acc[8][4];
#pragma unroll
  for (int tt = 0; tt < 8; tt++)
#pragma unroll
    for (int i = 0; i < 4; i++) acc[tt][i] = 0.f;
  for (int n = 0; n < 64; n++) {
    float4 h4 = *(const float4*)&Hs[n * 128 + pg * 4];
#pragma unroll
    for (int tt = 0; tt < 8; tt++) {
      float cv = Cs[(tg + tt) * 64 + n];
      acc[tt][0] += cv * h4.x; acc[tt][1] += cv * h4.y;
      acc[tt][2] += cv * h4.z; acc[tt][3] += cv * h4.w;
    }
  }
#pragma unroll
  for (int tt = 0; tt < 8; tt++) {
    int t = tg + tt;
    float dout = __expf(adt * (float)(t + 1));
    size_t row = (size_t)(b * L_ + l0 + t);
#pragma unroll
    for (int i = 0; i < 4; i++) {
      int p = pg * 4 + i;
      float g = __bfloat162float(vg[row * 4096 + 2048 + h * PS_ + p]);
      float yv = y[row * DI_ + h * PS_ + p] + acc[tt][i] * dout;
      yout[row * DI_ + h * PS_ + p] = __float2bfloat16(yv * (g / (1.f + __expf(-g))));
    }
  }
}

// ---------------- rope tables ----------------
__global__ void rope_fill_kernel(float* __restrict__ cosb, float* __restrict__ sinb) {
  int idx = blockIdx.x * 256 + threadIdx.x;
  int i = idx & 31, l = idx >> 5;
  float inv = __expf(-(2.0f * (float)i / (float)PA_) * logf(10000.0f));
  float ang = (float)l * inv;
  cosb[idx] = cosf(ang);
  sinb[idx] = sinf(ang);
}

// ---------------- per-head rmsnorm + rope (+gain), bf16 strided src -> packed bf16 dst ----------------
__global__ __launch_bounds__(256) void qknorm_rope_bf16_kernel(
    const __hip_bfloat16* __restrict__ src, int srcstride, int srcofs,
    __hip_bfloat16* __restrict__ dst, int nh,
    const float* __restrict__ cosb, const float* __restrict__ sinb,
    const float* __restrict__ gain) {
  int row = blockIdx.x * 4 + (threadIdx.x >> 6);
  int lane = threadIdx.x & 63;
  int h = row % nh;
  int tok = row / nh;
  int l = tok & (L_ - 1);
  float v = __bfloat162float(src[(size_t)tok * srcstride + srcofs + h * 64 + lane]);
  float ss = v * v;
  for (int o = 32; o > 0; o >>= 1) ss += __shfl_xor(ss, o, 64);
  v *= rsqrtf(ss * (1.f / PA_) + RMS_EPS_);
  float partner = __shfl_xor(v, 32, 64);
  int i = lane & 31;
  float cth = cosb[l * 32 + i], sth = sinb[l * 32 + i];
  float out = (lane < 32) ? (v * cth + partner * sth) : (v * cth - partner * sth);
  if (gain) out *= gain[h];
  dst[(size_t)tok * (nh * 64) + h * 64 + lane] = __float2bfloat16(out);
}

// ---------------- causal GQA flash attention, bf16 MFMA ----------------
__global__ __launch_bounds__(256) void attn_mfma_kernel(
    const unsigned short* __restrict__ qb, const unsigned short* __restrict__ kb,
    const unsigned short* __restrict__ vt, const float* __restrict__ qgain,
    __hip_bfloat16* __restrict__ ao) {
  __shared__ unsigned short Ks[64][72];
  __shared__ unsigned short Vs[64][72];
  __shared__ unsigned short Psm[4][16][72];
  int blk = blockIdx.x;
  int qi = blk & 15;
  int h  = (blk >> 4) & 15;
  int b  = blk >> 8;
  int hk = h >> 2;
  int tid = threadIdx.x;
  int w = tid >> 6, l = tid & 63;
  int l15 = l & 15, lg = l >> 4;
  int r0 = tid >> 3, s0 = tid & 7;
  float mstat = 8.0f * fabsf(qgain[h]);
  const unsigned short* kbase = kb + (size_t)b * L_ * (HKV_ * PA_) + hk * PA_ + s0 * 8;
  const unsigned short* vbase = vt + ((size_t)(b * HKV_ + hk) * PA_) * L_ + s0 * 8;

  for (int pass = 0; pass < 2; pass++) {
    int qt = pass ? (31 - qi) : qi;
    int q0 = qt * 64;
    int qw = q0 + w * 16;
    short8 qf[2];
    {
      size_t qrow = ((size_t)(b * L_ + qw + l15)) * (HA_ * PA_) + h * PA_;
      qf[0] = *(const short8*)&qb[qrow + lg * 8];
      qf[1] = *(const short8*)&qb[qrow + 32 + lg * 8];
    }
    f32x4 o_acc[4];
#pragma unroll
    for (int db = 0; db < 4; db++) o_acc[db] = (f32x4){0.f, 0.f, 0.f, 0.f};
    f32x4 lsum = (f32x4){0.f, 0.f, 0.f, 0.f};
    int nkt = qt + 1;
    short8 kr0 = *(const short8*)&kbase[(size_t)r0 * (HKV_ * PA_)];
    short8 kr1 = *(const short8*)&kbase[(size_t)(r0 + 32) * (HKV_ * PA_)];
    short8 vr0 = *(const short8*)&vbase[(size_t)r0 * L_];
    short8 vr1 = *(const short8*)&vbase[(size_t)(r0 + 32) * L_];
    for (int kt = 0; kt < nkt; kt++) {
      int k0 = kt * 64;
      __syncthreads();
      *(short8*)&Ks[r0][s0 * 8] = kr0;
      *(short8*)&Ks[r0 + 32][s0 * 8] = kr1;
      *(short8*)&Vs[r0][s0 * 8] = vr0;
      *(short8*)&Vs[r0 + 32][s0 * 8] = vr1;
      if (kt + 1 < nkt) {
        int k1 = k0 + 64;
        kr0 = *(const short8*)&kbase[(size_t)(k1 + r0) * (HKV_ * PA_)];
        kr1 = *(const short8*)&kbase[(size_t)(k1 + r0 + 32) * (HKV_ * PA_)];
        vr0 = *(const short8*)&vbase[(size_t)r0 * L_ + k1];
        vr1 = *(const short8*)&vbase[(size_t)(r0 + 32) * L_ + k1];
      }
      __syncthreads();
      f32x4 s_acc[4];
#pragma unroll
      for (int kb2 = 0; kb2 < 4; kb2++) {
        short8 b0 = *(const short8*)&Ks[kb2 * 16 + l15][lg * 8];
        short8 b1 = *(const short8*)&Ks[kb2 * 16 + l15][32 + lg * 8];
        f32x4 s = (f32x4){0.f, 0.f, 0.f, 0.f};
        s = __builtin_amdgcn_mfma_f32_16x16x32_bf16(qf[0], b0, s, 0, 0, 0);
        s = __builtin_amdgcn_mfma_f32_16x16x32_bf16(qf[1], b1, s, 0, 0, 0);
        s_acc[kb2] = s;
      }
      bool diag = (kt == qt);
#pragma unroll
      for (int kb2 = 0; kb2 < 4; kb2++) {
        int key = k0 + kb2 * 16 + l15;
#pragma unroll
        for (int reg = 0; reg < 4; reg++) {
          float p = __expf(s_acc[kb2][reg] * 0.125f - mstat);
          if (diag && key > qw + lg * 4 + reg) p = 0.f;
          lsum[reg] += p;
          __hip_bfloat16 hv = __float2bfloat16(p);
          Psm[w][lg * 4 + reg][kb2 * 16 + l15] = *(unsigned short*)&hv;
        }
      }
      asm volatile("s_waitcnt lgkmcnt(0)" ::: "memory");
#pragma unroll
      for (int ks = 0; ks < 2; ks++) {
        short8 pa = *(const short8*)&Psm[w][l15][ks * 32 + lg * 8];
#pragma unroll
        for (int db = 0; db < 4; db++) {
          short8 vb8 = *(const short8*)&Vs[db * 16 + l15][ks * 32 + lg * 8];
          o_acc[db] = __builtin_amdgcn_mfma_f32_16x16x32_bf16(pa, vb8, o_acc[db], 0, 0, 0);
        }
      }
    }
#pragma unroll
    for (int of = 1; of < 16; of <<= 1) {
      lsum[0] += __shfl_xor(lsum[0], of, 64);
      lsum[1] += __shfl_xor(lsum[1], of, 64);
      lsum[2] += __shfl_xor(lsum[2], of, 64);
      lsum[3] += __shfl_xor(lsum[3], of, 64);
    }
#pragma unroll
    for (int reg = 0; reg < 4; reg++) {
      float invl = 1.0f / lsum[reg];
      size_t row = (size_t)(b * L_ + qw + lg * 4 + reg);
#pragma unroll
      for (int db = 0; db < 4; db++)
        ao[row * D_ + h * PA_ + db * 16 + l15] = __float2bfloat16(o_acc[db][reg] * invl);
    }
  }
}

// ---------------- host ----------------
extern "C" void kernel_launch(void* const* d_in, const int* in_sizes, int n_in,
                              void* d_out, int out_size, void* d_ws, size_t ws_size,
                              hipStream_t stream) {
  (void)in_sizes; (void)n_in; (void)out_size; (void)ws_size;
  const float* x           = (const float*)d_in[0];
  const float* in_proj_w   = (const float*)d_in[1];
  const float* conv_w      = (const float*)d_in[2];
  const float* conv_b      = (const float*)d_in[3];
  const float* B_proj_w    = (const float*)d_in[4];
  const float* C_proj_w    = (const float*)d_in[5];
  const float* dt_bias     = (const float*)d_in[6];
  const float* A_log       = (const float*)d_in[7];
  const float* D_param     = (const float*)d_in[8];
  const float* out_proj_w  = (const float*)d_in[9];
  const float* resid_mix_m = (const float*)d_in[10];
  const float* mamba_scale = (const float*)d_in[11];
  const float* m_fc_w      = (const float*)d_in[12];
  const float* m_proj_w    = (const float*)d_in[13];
  const float* m_mlp_scale = (const float*)d_in[14];
  const float* resid_mix_a = (const float*)d_in[15];
  const float* q_w         = (const float*)d_in[16];
  const float* k_w         = (const float*)d_in[17];
  const float* v_w         = (const float*)d_in[18];
  const float* o_w         = (const float*)d_in[19];
  const float* q_gain      = (const float*)d_in[20];
  const float* attn_scale  = (const float*)d_in[21];
  const float* a_fc_w      = (const float*)d_in[22];
  const float* a_proj_w    = (const float*)d_in[23];
  const float* a_mlp_scale = (const float*)d_in[24];
  float* ws  = (float*)d_ws;
  float* out = (float*)d_out;

  // ---- workspace layout (float units) ----
  float* xm    = ws;
  float* vgR   = ws + 4194304;
  float* xvR   = ws + 12582912;
  float* stR   = ws + 20971520;
  float* nbR   = ws + 29360128;
  float* xmbR  = ws + 31457280;
  float* BCR   = ws + 33554432;
  float* WtR   = ws + 37748736;
  float* cosb  = ws + 51642368;
  float* sinb  = cosb + 65536;

  __hip_bfloat16* vg   = (__hip_bfloat16*)vgR;      // [NT][4096] bf16 (value|gate)
  __hip_bfloat16* qkvb = (__hip_bfloat16*)vgR;      // [NT][1536] bf16 (attn phase)
  float*          yv   = xvR;                       // y f32 [NT][2048]
  float*          st   = stR;
  __hip_bfloat16* hb   = (__hip_bfloat16*)stR;
  __hip_bfloat16* nbb  = (__hip_bfloat16*)nbR;
  __hip_bfloat16* xmb  = (__hip_bfloat16*)xmbR;
  __hip_bfloat16* ybb  = (__hip_bfloat16*)nbR;
  __hip_bfloat16* BCm  = (__hip_bfloat16*)BCR;
  __hip_bfloat16* qbb  = (__hip_bfloat16*)xvR;                 // [NT][1024]
  __hip_bfloat16* kbb  = (__hip_bfloat16*)(xvR + 2097152);     // [NT][256]
  __hip_bfloat16* vtb  = (__hip_bfloat16*)(xvR + 2621440);     // [2][256][2048]
  __hip_bfloat16* aob  = (__hip_bfloat16*)(xvR + 3145728);     // [NT][1024]

  __hip_bfloat16* Wt = (__hip_bfloat16*)WtR;
  size_t o_in  = 0;
  size_t o_B   = o_in  + (size_t)4096 * 1024;
  size_t o_out = o_B   + (size_t)2048 * 1024;
  size_t o_mfc = o_out + (size_t)1024 * 2048;
  size_t o_mpj = o_mfc + (size_t)4096 * 1024;
  size_t o_qkv = o_mpj + (size_t)1024 * 4096;
  size_t o_o   = o_qkv + (size_t)1536 * 1024;
  size_t o_afc = o_o   + (size_t)1024 * 1024;
  size_t o_apj = o_afc + (size_t)4096 * 1024;

#define TCVT(Wp, off, K, N) \
  transpose_cvt<<<dim3((N) / 32, (K) / 32), 256, 0, stream>>>((Wp), Wt + (off), (K), (N), (N))
  TCVT(in_proj_w,  o_in,  1024, 4096);
  TCVT(B_proj_w,   o_B,   1024, 1024);
  TCVT(C_proj_w,   o_B + (size_t)1024 * 1024, 1024, 1024);
  TCVT(out_proj_w, o_out, 2048, 1024);
  TCVT(m_fc_w,     o_mfc, 1024, 4096);
  TCVT(m_proj_w,   o_mpj, 4096, 1024);
  TCVT(q_w,        o_qkv, 1024, 1024);
  TCVT(k_w,        o_qkv + (size_t)1024 * 1024, 1024, 256);
  TCVT(v_w,        o_qkv + (size_t)1280 * 1024, 1024, 256);
  TCVT(o_w,        o_o,   1024, 1024);
  TCVT(a_fc_w,     o_afc, 1024, 4096);
  TCVT(a_proj_w,   o_apj, 4096, 1024);
#undef TCVT

#define GEMM(BN, Abuf, Woff, Cfp, Cbp, basep, scalep, N, K, mode, rsh) \
  gemm_bf16_t<BN><<<32 * ((N) / (BN)), 256, 0, stream>>>( \
      (const unsigned short*)(Abuf), (const unsigned short*)(Wt + (Woff)), \
      (Cfp), (Cbp), (basep), (scalep), (N), (K), (N) / (BN), (mode), (rsh))
#define GEMM64(Abuf, Woff, Cfp, Cbop, basep, scalep, N, K, mode) \
  gemm64<<<64 * ((N) / 64), 256, 0, stream>>>( \
      (const unsigned short*)(Abuf), (const unsigned short*)(Wt + (Woff)), \
      (Cfp), (Cbop), (basep), (scalep), (N), (K), (mode))
#define GEMM256(MODE, Abuf, Woff, Cbp) \
  gemm256_k32<MODE><<<256, 512, 0, stream>>>( \
      (const unsigned short*)(Abuf), (const unsigned short*)(Wt + (Woff)), \
      (Cbp), 4096, 1024)

  // --- mamba branch ---
  mix_rms_kernel<<<NT_, 256, 0, stream>>>(x, x, resid_mix_m, xm, nbb, xmb);
  GEMM256(2, nbb, o_in, vg);
  GEMM(128, xmb, o_B, (float*)0, BCm, (const float*)0, (const float*)0, 2048, 1024, 2, 0);
  scanAF_kernel<<<B_ * HS_ * NC_, 256, 0, stream>>>(vg, BCm, conv_w, conv_b,
                                                    dt_bias, A_log, D_param, st, yv);
  scanB1_kernel<<<B_ * HS_ * 4, 256, 0, stream>>>(st, dt_bias, A_log);
  scanB2_kernel<<<B_ * HS_ * NC_, 256, 0, stream>>>(BCm, st, vg, dt_bias, A_log, yv, ybb);
  GEMM64(ybb, o_out, xm, (__hip_bfloat16*)0, xm, mamba_scale, 1024, 2048, 3);
  // --- mamba MLP ---
  rms_kernel<<<NT_, 256, 0, stream>>>(xm, nbb);
  GEMM256(1, nbb, o_mfc, hb);
  GEMM64(hb, o_mpj, xm, (__hip_bfloat16*)0, xm, m_mlp_scale, 1024, 4096, 3);
  // --- attention branch ---
  mix_rms_kernel<<<NT_, 256, 0, stream>>>(xm, x, resid_mix_a, xm, nbb, (__hip_bfloat16*)0);
  GEMM64(nbb, o_qkv, (float*)0, qkvb, (const float*)0, (const float*)0, 1536, 1024, 2);
  rope_fill_kernel<<<L_ * 32 / 256, 256, 0, stream>>>(cosb, sinb);
  qknorm_rope_bf16_kernel<<<NT_ * HA_ / 4, 256, 0, stream>>>(qkvb, 1536, 0, qbb, HA_, cosb, sinb, q_gain);
  qknorm_rope_bf16_kernel<<<NT_ * HKV_ / 4, 256, 0, stream>>>(qkvb, 1536, 1024, kbb, HKV_, cosb, sinb, (const float*)0);
  transpose_bf16<<<dim3(256 / 32, 2048 / 32), 256, 0, stream>>>(
      (const unsigned short*)qkvb + 1280, (unsigned short*)vtb, 2048, 256, 1536);
  transpose_bf16<<<dim3(256 / 32, 2048 / 32), 256, 0, stream>>>(
      (const unsigned short*)qkvb + (size_t)L_ * 1536 + 1280,
      (unsigned short*)vtb + (size_t)256 * L_, 2048, 256, 1536);
  attn_mfma_kernel<<<B_ * HA_ * 16, 256, 0, stream>>>(
      (const unsigned short*)qbb, (const unsigned short*)kbb, (const unsigned short*)vtb,
      q_gain, aob);
  GEMM64(aob, o_o, xm, (__hip_bfloat16*)0, xm, attn_scale, 1024, 1024, 3);
  // --- attention MLP ---
  rms_kernel<<<NT_, 256, 0, stream>>>(xm, nbb);
  GEMM256(1, nbb, o_afc, hb);
  GEMM64(hb, o_apj, out, (__hip_bfloat16*)0, xm, a_mlp_scale, 1024, 4096, 3);
#undef GEMM
#undef GEMM64
#undef GEMM256
}